// Round 6
// baseline (4608.126 us; speedup 1.0000x reference)
//
#include <hip/hip_runtime.h>
#include <hip/hip_bf16.h>
#include <math.h>
#include <stddef.h>

namespace {

constexpr int V = 32000, H = 512, L = 4, A = 384, B = 2, T = 32, FF = 2048;
constexpr long LOGITS = (long)B * T * V;   // 2,048,000
constexpr int GRID = 256, NT = 512;
constexpr int NXR = 40;                    // roles (blocks) per x layer-set
constexpr int NGB = 8;                     // ghost blocks per (l,b)
constexpr float EPS = 1e-5f;

typedef short bf16x8 __attribute__((ext_vector_type(8)));
typedef float f32x4 __attribute__((ext_vector_type(4)));

struct WS {
  // ---- zeroed region ----
  unsigned gbar_cnt, gbar_gen;
  unsigned pad0[62];
  unsigned p1f[L][48], p2f[L][48], p3f[L][48];
  unsigned gcol_cnt[L][T][B];
  unsigned pad2[64];
  float gcol[L][T][B][H];          // atomicAdd accumulated
  // ---- not zeroed (fully written before read every launch) ----
  float uv[T][L][B][A + H];
  float outs[T][B][H];
  float lnouts[T * B][H];
  float xn[3][T][B][H];            // layer handoff l -> l+1
  float hbuf[L][2][B][FF];         // t-parity double buffer
  float initcol[L * B * H];
  float bus[4];
  uint4 bpk[L][2][2][16][32][64];  // ghost bf16 frag-packed W (hi/lo split)
};

union __align__(16) SMem {
  struct { float s[16][516]; uint4 Ahi[16][64]; uint4 Alo[16][64]; } g;   // ~66 KB
  struct {
    unsigned wp[23][256];          // Wp slice, bf16 pair (k=2m, 2m+1)
    unsigned w1[52][256];          // W1 slice
    unsigned w2[13][1024];         // W2 slice, pair (k, k+1024)
    float xm[2][512];
    float lnx[2][512];
    float h[2][2048];
    float2 red[8];
  } xp;                            // ~151 KB
  struct { float tile[125][64]; } hd;
};

__device__ __forceinline__ float dot4(const float4& a, const float4& b) {
  return a.x * b.x + a.y * b.y + a.z * b.z + a.w * b.w;
}
__device__ __forceinline__ unsigned bf16r(float f) {
  unsigned u = __float_as_uint(f);
  return (u + 0x7fffu + ((u >> 16) & 1u)) >> 16;
}
__device__ __forceinline__ float aload(const float* p) {
  return __hip_atomic_load(p, __ATOMIC_RELAXED, __HIP_MEMORY_SCOPE_AGENT);
}
__device__ __forceinline__ void astore(float* p, float v) {
  __hip_atomic_store(p, v, __ATOMIC_RELAXED, __HIP_MEMORY_SCOPE_AGENT);
}
__device__ __forceinline__ float2 aload2(const float* p) {
  unsigned long long u = __hip_atomic_load((const unsigned long long*)p,
                                           __ATOMIC_RELAXED, __HIP_MEMORY_SCOPE_AGENT);
  return __builtin_bit_cast(float2, u);
}
__device__ __forceinline__ f32x4 mfma16(bf16x8 a, bf16x8 b, f32x4 c) {
  return __builtin_amdgcn_mfma_f32_16x16x32_bf16(a, b, c, 0, 0, 0);
}

__device__ void wait_u32(unsigned* p, unsigned target) {
  int spin = 0;
  while (__hip_atomic_load(p, __ATOMIC_RELAXED, __HIP_MEMORY_SCOPE_AGENT) < target) {
    __builtin_amdgcn_s_sleep(8);
    if ((++spin & 63) == 0)
      (void)__hip_atomic_load(p, __ATOMIC_ACQUIRE, __HIP_MEMORY_SCOPE_AGENT);
  }
}

__device__ void gbar(WS* ws) {
  __syncthreads();
  if (threadIdx.x == 0) {
    __threadfence();
    unsigned g = __hip_atomic_load(&ws->gbar_gen, __ATOMIC_RELAXED, __HIP_MEMORY_SCOPE_AGENT);
    unsigned a = __hip_atomic_fetch_add(&ws->gbar_cnt, 1u, __ATOMIC_ACQ_REL, __HIP_MEMORY_SCOPE_AGENT);
    if (a == (unsigned)(GRID - 1)) {
      __hip_atomic_store(&ws->gbar_cnt, 0u, __ATOMIC_RELAXED, __HIP_MEMORY_SCOPE_AGENT);
      __hip_atomic_fetch_add(&ws->gbar_gen, 1u, __ATOMIC_RELEASE, __HIP_MEMORY_SCOPE_AGENT);
    } else {
      wait_u32(&ws->gbar_gen, g + 1);
    }
    __threadfence();
  }
  __syncthreads();
}

// all-set flag-array poll (wave 0 ballots, no atomic contention)
__device__ void poll_flags(unsigned* f, int n, unsigned tgt) {
  if (threadIdx.x < 64) {
    int spin = 0;
    int idx = (int)threadIdx.x < n ? (int)threadIdx.x : 0;
    for (;;) {
      unsigned v = ((int)threadIdx.x < n)
          ? __hip_atomic_load(&f[threadIdx.x], __ATOMIC_RELAXED, __HIP_MEMORY_SCOPE_AGENT)
          : tgt;
      if (__all(v >= tgt)) break;
      __builtin_amdgcn_s_sleep(4);
      if ((++spin & 63) == 0)
        (void)__hip_atomic_load(&f[idx], __ATOMIC_ACQUIRE, __HIP_MEMORY_SCOPE_AGENT);
    }
  }
  __syncthreads();
}

__device__ void setf(unsigned* p, unsigned v) {
  __builtin_amdgcn_s_waitcnt(0);   // all prior stores globally visible
  __syncthreads();                 // all waves done
  if (threadIdx.x == 0)
    __hip_atomic_store(p, v, __ATOMIC_RELEASE, __HIP_MEMORY_SCOPE_AGENT);
}

__device__ float2 wred2(float2 v) {
  #pragma unroll
  for (int off = 1; off < 64; off <<= 1) {
    v.x += __shfl_xor(v.x, off);
    v.y += __shfl_xor(v.y, off);
  }
  return v;
}

__device__ float2 block_red2(float2 v, SMem& sm) {
  v = wred2(v);
  int w = threadIdx.x >> 6;
  __syncthreads();
  if ((threadIdx.x & 63) == 0) sm.xp.red[w] = v;
  __syncthreads();
  float2 s{0.f, 0.f};
  #pragma unroll
  for (int q = 0; q < 8; ++q) { s.x += sm.xp.red[q].x; s.y += sm.xp.red[q].y; }
  return s;
}

__device__ void ln512(SMem& sm, const float* in, float* outp,
                      const float* w, const float* b) {
  int tid = threadIdx.x;
  float xv = in[tid];
  float m = block_red2({xv, 0.f}, sm).x * (1.f / H);
  float d = xv - m;
  float var = block_red2({d * d, 0.f}, sm).x * (1.f / H);
  float inv = rsqrtf(var + EPS);
  outp[tid] = d * inv * w[tid] + b[tid];
  __syncthreads();
}

// dual-batch LN over sm.xp.xm -> sm.xp.lnx
__device__ void ln2pair(SMem& sm, const float* w, const float* b) {
  int tid = threadIdx.x;
  float x0 = sm.xp.xm[0][tid], x1 = sm.xp.xm[1][tid];
  float2 mm = block_red2({x0, x1}, sm);
  float d0 = x0 - mm.x * (1.f / H), d1 = x1 - mm.y * (1.f / H);
  float2 vv = block_red2({d0 * d0, d1 * d1}, sm);
  float i0 = rsqrtf(vv.x * (1.f / H) + EPS), i1 = rsqrtf(vv.y * (1.f / H) + EPS);
  float wv_ = w[tid], bv = b[tid];
  sm.xp.lnx[0][tid] = d0 * i0 * wv_ + bv;
  sm.xp.lnx[1][tid] = d1 * i1 * wv_ + bv;
  __syncthreads();
}

__device__ __forceinline__ float2 d8(uint4 wq, const float* xr0, const float* xr1) {
  float2 a{0.f, 0.f};
  unsigned u[4] = {wq.x, wq.y, wq.z, wq.w};
  #pragma unroll
  for (int j = 0; j < 4; ++j) {
    float wl = __uint_as_float(u[j] << 16);
    float wh = __uint_as_float(u[j] & 0xffff0000u);
    a.x = fmaf(wl, xr0[2 * j], fmaf(wh, xr0[2 * j + 1], a.x));
    a.y = fmaf(wl, xr1[2 * j], fmaf(wh, xr1[2 * j + 1], a.y));
  }
  return a;
}

// ---------------------------------------------------------------- ghost (MFMA)
__device__ void ghost_mfma(int l, int b, int r0, WS* ws, SMem& sm,
                           const float* __restrict__ states, float* __restrict__ fs) {
  const int tid = threadIdx.x, wv = tid >> 6, lane = tid & 63;
  for (int i = tid; i < 16 * 512; i += NT) {
    int r = i >> 9, k = i & 511;
    sm.g.s[r][k] = states[((((long)l * B + b) * H) + A + r0 + r) * H + k];
  }
  __syncthreads();
  const int ct0 = wv * 4;

  for (int rec = 0; rec < 2 * T; ++rec) {
    for (int q = tid; q < 1024; q += NT) {
      int kt = q >> 6, ln = q & 63;
      int row = ln & 15, kb = kt * 32 + ((ln >> 4) << 3);
      unsigned h[8], lo[8];
      #pragma unroll
      for (int j = 0; j < 8; ++j) {
        float v = sm.g.s[row][kb + j];
        h[j] = bf16r(v);
        float hf = __uint_as_float(h[j] << 16);
        lo[j] = bf16r(v - hf);
      }
      uint4 uh, ul;
      uh.x = h[0] | (h[1] << 16);  uh.y = h[2] | (h[3] << 16);
      uh.z = h[4] | (h[5] << 16);  uh.w = h[6] | (h[7] << 16);
      ul.x = lo[0] | (lo[1] << 16); ul.y = lo[2] | (lo[3] << 16);
      ul.z = lo[4] | (lo[5] << 16); ul.w = lo[6] | (lo[7] << 16);
      sm.g.Ahi[kt][ln] = uh;
      sm.g.Alo[kt][ln] = ul;
    }
    __syncthreads();

    f32x4 accg[4], acct[4];
    #pragma unroll
    for (int c = 0; c < 4; ++c) { accg[c] = {0.f, 0.f, 0.f, 0.f}; acct[c] = {0.f, 0.f, 0.f, 0.f}; }
    for (int kt = 0; kt < 16; ++kt) {
      bf16x8 ahi = __builtin_bit_cast(bf16x8, sm.g.Ahi[kt][lane]);
      bf16x8 alo = __builtin_bit_cast(bf16x8, sm.g.Alo[kt][lane]);
      #pragma unroll
      for (int c = 0; c < 4; ++c) {
        int ct = ct0 + c;
        bf16x8 bgh = __builtin_bit_cast(bf16x8, ws->bpk[l][0][0][kt][ct][lane]);
        bf16x8 bgl = __builtin_bit_cast(bf16x8, ws->bpk[l][0][1][kt][ct][lane]);
        bf16x8 bth = __builtin_bit_cast(bf16x8, ws->bpk[l][1][0][kt][ct][lane]);
        bf16x8 btl = __builtin_bit_cast(bf16x8, ws->bpk[l][1][1][kt][ct][lane]);
        accg[c] = mfma16(ahi, bgh, accg[c]);
        accg[c] = mfma16(ahi, bgl, accg[c]);
        accg[c] = mfma16(alo, bgh, accg[c]);
        acct[c] = mfma16(ahi, bth, acct[c]);
        acct[c] = mfma16(ahi, btl, acct[c]);
        acct[c] = mfma16(alo, bth, acct[c]);
      }
    }

    const int t = rec >> 1;
    const bool pub = (rec & 1) != 0;
    const int rb = (lane >> 4) * 4;
    #pragma unroll
    for (int c = 0; c < 4; ++c) {
      int col = (ct0 + c) * 16 + (lane & 15);
      float cs = 0.f;
      #pragma unroll
      for (int r = 0; r < 4; ++r) {
        float sig = 1.f / (1.f + expf(-accg[c][r]));
        float th = tanhf(acct[c][r]);
        float nv = sm.g.s[rb + r][col] + sig * th;
        sm.g.s[rb + r][col] = nv;
        cs += nv;
      }
      if (pub) {
        cs += __shfl_xor(cs, 16);
        cs += __shfl_xor(cs, 32);
        if (lane < 16)
          __hip_atomic_fetch_add(&ws->gcol[l][t][b][col], cs,
                                 __ATOMIC_RELAXED, __HIP_MEMORY_SCOPE_AGENT);
      }
    }
    if (pub) {
      __builtin_amdgcn_s_waitcnt(0);
      __syncthreads();
      if (tid == 0)
        __hip_atomic_fetch_add(&ws->gcol_cnt[l][t][b], 1u,
                               __ATOMIC_RELEASE, __HIP_MEMORY_SCOPE_AGENT);
    } else {
      __syncthreads();
    }
  }
  for (int i = tid; i < 16 * 512; i += NT) {
    int r = i >> 9, k = i & 511;
    fs[((((long)l * B + b) * H) + A + r0 + r) * H + k] = sm.g.s[r][k];
  }
}

// ---------------------------------------------------------------- x layer-set
__device__ void x_set(int l, int role, WS* ws, SMem& sm,
                      const int* ids, const float* emb,
                      const float* nx_w, const float* nx_b,
                      const float* Wp, const float* bp,
                      const float* ns_w, const float* ns_b,
                      const float* W1, const float* b1,
                      const float* W2, const float* b2) {
  const int tid = threadIdx.x, wv = tid >> 6, lane = tid & 63;
  const long wb = (long)l * (A + H);
  const int p0 = (role * 896) / NXR,  p1 = ((role + 1) * 896) / NXR;
  const int a0 = (role * 2048) / NXR, a1 = ((role + 1) * 2048) / NXR;
  const int c0 = (role * 512) / NXR,  c1 = ((role + 1) * 512) / NXR;

  // ---- one-time: weight slices -> LDS (bf16-packed) ----
  for (int i = tid; i < (p1 - p0) * 256; i += NT) {
    int row = i >> 8, m = i & 255;
    const float* s = Wp + (wb + p0 + row) * H + 2 * m;
    sm.xp.wp[row][m] = bf16r(s[0]) | (bf16r(s[1]) << 16);
  }
  for (int i = tid; i < (a1 - a0) * 256; i += NT) {
    int row = i >> 8, m = i & 255;
    const float* s = W1 + ((long)l * FF + a0 + row) * H + 2 * m;
    sm.xp.w1[row][m] = bf16r(s[0]) | (bf16r(s[1]) << 16);
  }
  for (int i = tid; i < (c1 - c0) * 1024; i += NT) {
    int row = i >> 10, q = i & 1023;
    const float* s = W2 + ((long)l * H + c0 + row) * FF + q;
    sm.xp.w2[row][q] = bf16r(s[0]) | (bf16r(s[1024]) << 16);
  }
  const float ic0 = ws->initcol[(l * B + 0) * H + tid];
  const float ic1 = ws->initcol[(l * B + 1) * H + tid];
  const float BU = ws->bus[l];
  const float bpA = bp[wb + A + tid];
  float as0 = 0.f, as1 = 0.f;
  __syncthreads();

  for (int t = 0; t < T; ++t) {
    // ---- P0: x input ----
    if (l == 0) {
      sm.xp.xm[0][tid] = emb[(long)ids[t] * H + tid];
      sm.xp.xm[1][tid] = emb[(long)ids[T + t] * H + tid];
    } else {
      poll_flags(ws->p3f[l - 1], NXR, (unsigned)(t + 1));
      sm.xp.xm[0][tid] = aload(&ws->xn[l - 1][t][0][tid]);
      sm.xp.xm[1][tid] = aload(&ws->xn[l - 1][t][1][tid]);
    }
    __syncthreads();
    // ---- P1: LN1 + Wp slice ----
    ln2pair(sm, nx_w + l * H, nx_b + l * H);
    float xr0[8], xr1[8];
    #pragma unroll
    for (int j = 0; j < 8; ++j) {
      xr0[j] = sm.xp.lnx[0][lane * 8 + j];
      xr1[j] = sm.xp.lnx[1][lane * 8 + j];
    }
    for (int row = p0 + wv; row < p1; row += 8) {
      uint4 wq = *(const uint4*)&sm.xp.wp[row - p0][lane * 4];
      float2 acc = wred2(d8(wq, xr0, xr1));
      if (lane == 0) {
        float bb = bp[wb + row];
        astore(&ws->uv[t][l][0][row], acc.x + bb);
        astore(&ws->uv[t][l][1][row], acc.y + bb);
      }
    }
    setf(&ws->p1f[l][role], (unsigned)(t + 1));
    poll_flags(ws->p1f[l], NXR, (unsigned)(t + 1));
    // ---- P2: U1, asum, xm, LN2, W1 slice ----
    float2 us{0.f, 0.f};
    if (tid < A) {
      us.x = aload(&ws->uv[t][l][0][tid]);
      us.y = aload(&ws->uv[t][l][1][tid]);
    }
    float2 U1 = block_red2(us, sm);
    float v0 = aload(&ws->uv[t][l][0][A + tid]);
    float v1 = aload(&ws->uv[t][l][1][A + tid]);
    as0 += U1.x * v0;
    as1 += U1.y * v1;
    if (tid == 0) {
      wait_u32(&ws->gcol_cnt[l][t][0], NGB);
      wait_u32(&ws->gcol_cnt[l][t][1], NGB);
    }
    __syncthreads();
    float gc0 = aload(&ws->gcol[l][t][0][tid]);
    float gc1 = aload(&ws->gcol[l][t][1][tid]);
    float tb = (float)(t + 1) * BU * bpA;
    sm.xp.xm[0][tid] += (as0 + ic0 + tb + gc0) * (1.f / H);
    sm.xp.xm[1][tid] += (as1 + ic1 + tb + gc1) * (1.f / H);
    ln2pair(sm, ns_w + l * H, ns_b + l * H);
    #pragma unroll
    for (int j = 0; j < 8; ++j) {
      xr0[j] = sm.xp.lnx[0][lane * 8 + j];
      xr1[j] = sm.xp.lnx[1][lane * 8 + j];
    }
    for (int row = a0 + wv; row < a1; row += 8) {
      uint4 wq = *(const uint4*)&sm.xp.w1[row - a0][lane * 4];
      float2 acc = wred2(d8(wq, xr0, xr1));
      if (lane == 0) {
        float bb = b1[(long)l * FF + row];
        float z0 = acc.x + bb, z1 = acc.y + bb;
        astore(&ws->hbuf[l][t & 1][0][row], 0.5f * z0 * (1.f + erff(z0 * 0.70710678118f)));
        astore(&ws->hbuf[l][t & 1][1][row], 0.5f * z1 * (1.f + erff(z1 * 0.70710678118f)));
      }
    }
    setf(&ws->p2f[l][role], (unsigned)(t + 1));
    poll_flags(ws->p2f[l], NXR, (unsigned)(t + 1));
    // ---- P3: gather h, W2 slice, residual, publish ----
    for (int pidx = tid; pidx < 2048; pidx += NT) {
      int b = pidx >> 10, m = pidx & 1023;
      float2 hv = aload2(&ws->hbuf[l][t & 1][b][2 * m]);
      *(float2*)&sm.xp.h[b][2 * m] = hv;
    }
    __syncthreads();
    for (int row = c0 + wv; row < c1; row += 8) {
      float2 acc{0.f, 0.f};
      #pragma unroll
      for (int qq = 0; qq < 16; ++qq) {
        unsigned w = sm.xp.w2[row - c0][qq * 64 + lane];
        float wl = __uint_as_float(w << 16);
        float wh = __uint_as_float(w & 0xffff0000u);
        int k = qq * 64 + lane;
        acc.x += wl * sm.xp.h[0][k] + wh * sm.xp.h[0][k + 1024];
        acc.y += wl * sm.xp.h[1][k] + wh * sm.xp.h[1][k + 1024];
      }
      acc = wred2(acc);
      if (lane == 0) {
        float bb = b2[(long)l * H + row];
        float o0 = sm.xp.xm[0][row] + acc.x + bb;
        float o1 = sm.xp.xm[1][row] + acc.y + bb;
        if (l == L - 1) {
          astore(&ws->outs[t][0][row], o0);
          astore(&ws->outs[t][1][row], o1);
        } else {
          astore(&ws->xn[l][t][0][row], o0);
          astore(&ws->xn[l][t][1][row], o1);
        }
      }
    }
    setf(&ws->p3f[l][role], (unsigned)(t + 1));
  }
}

// ---------------------------------------------------------------- prologue pack
__global__ __launch_bounds__(256) void pack_kernel(const float* __restrict__ Wg,
                                                   const float* __restrict__ Wt,
                                                   const float* __restrict__ states,
                                                   const float* __restrict__ bp,
                                                   WS* ws) {
  const int bid = blockIdx.x, tid = threadIdx.x;
  if (bid < 1024) {
    #pragma unroll
    for (int rep = 0; rep < 2; ++rep) {
      unsigned f = (unsigned)bid * 512u + (unsigned)rep * 256u + (unsigned)tid;
      int lane = f & 63, ct = (f >> 6) & 31, kt = (f >> 11) & 15;
      int split = (f >> 15) & 1, mat = (f >> 16) & 1, l = f >> 17;
      int o = ct * 16 + (lane & 15), kb = kt * 32 + ((lane >> 4) << 3);
      const float* src = (mat ? Wt : Wg) + ((long)l * H + o) * H + kb;
      unsigned v8[8];
      #pragma unroll
      for (int j = 0; j < 8; ++j) {
        float w = src[j];
        unsigned h = bf16r(w);
        if (split) {
          float hf = __uint_as_float(h << 16);
          h = bf16r(w - hf);
        }
        v8[j] = h;
      }
      uint4 u;
      u.x = v8[0] | (v8[1] << 16); u.y = v8[2] | (v8[3] << 16);
      u.z = v8[4] | (v8[5] << 16); u.w = v8[6] | (v8[7] << 16);
      ws->bpk[l][mat][split][kt][ct][lane] = u;
    }
  } else if (bid < 1032) {
    int lb = bid - 1024, l = lb >> 1, b = lb & 1;
    #pragma unroll
    for (int half = 0; half < 2; ++half) {
      int col = tid + half * 256;
      float acc = 0.f;
      for (int i = 0; i < A; ++i)
        acc += states[(((long)l * B + b) * H + i) * H + col];
      ws->initcol[(l * B + b) * H + col] = acc;
    }
  } else {
    __shared__ float tmp[256];
    int l = tid >> 6, i = tid & 63;
    float p = 0.f;
    for (int j = 0; j < 6; ++j) p += bp[(long)l * (A + H) + j * 64 + i];
    tmp[tid] = p;
    __syncthreads();
    if (tid < 4) {
      float s = 0.f;
      for (int q = 0; q < 64; ++q) s += tmp[tid * 64 + q];
      ws->bus[tid] = s;
    }
  }
}

// ---------------------------------------------------------------- main kernel
__global__ __launch_bounds__(NT, 1) void vega_kernel(
    const int* __restrict__ ids, const float* __restrict__ states,
    const float* __restrict__ emb,
    const float* __restrict__ nx_w, const float* __restrict__ nx_b,
    const float* __restrict__ Wp, const float* __restrict__ bp,
    const float* __restrict__ ns_w, const float* __restrict__ ns_b,
    const float* __restrict__ W1, const float* __restrict__ b1,
    const float* __restrict__ W2, const float* __restrict__ b2,
    const float* __restrict__ on_w, const float* __restrict__ on_b,
    const float* __restrict__ head_W, const float* __restrict__ head_b,
    float* __restrict__ out, WS* ws) {
  __shared__ SMem sm;
  const int bid = blockIdx.x, tid = threadIdx.x;
  float* fs = out + LOGITS;

  const int c = bid & 7, j = bid >> 3;
  if (c < 4 && j < 16) {
    // ghost on XCDs 0-3 (layer c pinned -> bpk L2-resident)
    ghost_mfma(c, j >> 3, (j & 7) * 16, ws, sm, states, fs);
  } else if (c >= 4) {
    x_set(c - 4, j, ws, sm, ids, emb, nx_w, nx_b, Wp, bp,
          ns_w, ns_b, W1, b1, W2, b2);
  } else if (j < 24) {
    x_set(c, 32 + (j - 16), ws, sm, ids, emb, nx_w, nx_b, Wp, bp,
          ns_w, ns_b, W1, b1, W2, b2);
  }
  // remaining blocks idle until epilogue

  gbar(ws);

  // -------- E1: active fstates reconstruction + final LN of outs --------
  if (bid < 192) {
    int lb = bid / 24, sub = bid % 24;
    int l = lb >> 1, b = lb & 1, r0 = sub * 16;
    long base = (long)l * (A + H);
    float bv = bp[base + A + tid];
    float acc[16];
    #pragma unroll
    for (int q = 0; q < 16; ++q) acc[q] = 32.f * bp[base + r0 + q] * bv;
    for (int t2 = 0; t2 < T; ++t2) {
      float vv = ws->uv[t2][l][b][A + tid];
      const float* u = &ws->uv[t2][l][b][0];
      #pragma unroll
      for (int q = 0; q < 16; ++q) acc[q] = fmaf(u[r0 + q], vv, acc[q]);
    }
    #pragma unroll
    for (int q = 0; q < 16; ++q)
      fs[(((long)l * B + b) * H + (r0 + q)) * H + tid] =
          states[(((long)l * B + b) * H + (r0 + q)) * H + tid] + acc[q];
  }
  if (bid < T * B) {
    int row = bid, t = row >> 1, b = row & 1;
    ln512(sm, ws->outs[t][b], ws->lnouts[row], on_w, on_b);
  }

  gbar(ws);

  // -------- E2: head GEMM (64 rows x 125 vocab per block, K=512) --------
  {
    const int wv = tid >> 6, lane = tid & 63;
    const long vbase = (long)bid * 125;
    float acc[16];
    #pragma unroll
    for (int q = 0; q < 16; ++q) acc[q] = 0.f;
    for (int cc = 0; cc < 8; ++cc) {
      float4 xr[16];
      #pragma unroll
      for (int q = 0; q < 16; ++q)
        xr[q] = *(const float4*)&ws->lnouts[lane][cc * 64 + q * 4];
      #pragma unroll
      for (int vi = 0; vi < 16; ++vi) {
        int vloc = vi * 8 + wv;
        if (vloc < 125) {
          const float4* wp_ = (const float4*)(head_W + (vbase + vloc) * H + cc * 64);
          float s = 0.f;
          #pragma unroll
          for (int q = 0; q < 16; ++q) s += dot4(xr[q], wp_[q]);
          acc[vi] += s;
        }
      }
    }
    #pragma unroll
    for (int vi = 0; vi < 16; ++vi) {
      int vloc = vi * 8 + wv;
      if (vloc < 125) sm.hd.tile[vloc][lane] = acc[vi] + head_b[vbase + vloc];
    }
    __syncthreads();
    for (int idx = tid; idx < 64 * 125; idx += NT) {
      int row = idx / 125, vl = idx % 125;
      int t = row >> 1, b = row & 1;
      out[((long)(b * T + t)) * V + vbase + vl] = sm.hd.tile[vl][row];
    }
  }
}

}  // namespace

extern "C" void kernel_launch(void* const* d_in, const int* in_sizes, int n_in,
                              void* d_out, int out_size, void* d_ws, size_t ws_size,
                              hipStream_t stream) {
  (void)in_sizes; (void)n_in; (void)out_size; (void)ws_size;
  const int*   ids    = (const int*)d_in[0];
  const float* states = (const float*)d_in[1];
  const float* emb    = (const float*)d_in[2];
  const float* nx_w   = (const float*)d_in[3];
  const float* nx_b   = (const float*)d_in[4];
  const float* Wp     = (const float*)d_in[5];
  const float* bp     = (const float*)d_in[6];
  const float* Wg     = (const float*)d_in[7];
  const float* Wt     = (const float*)d_in[8];
  const float* ns_w   = (const float*)d_in[9];
  const float* ns_b   = (const float*)d_in[10];
  const float* W1     = (const float*)d_in[11];
  const float* b1     = (const float*)d_in[12];
  const float* W2     = (const float*)d_in[13];
  const float* b2     = (const float*)d_in[14];
  const float* on_w   = (const float*)d_in[15];
  const float* on_b   = (const float*)d_in[16];
  const float* head_W = (const float*)d_in[17];
  const float* head_b = (const float*)d_in[18];
  float* out = (float*)d_out;
  WS* ws = (WS*)d_ws;

  hipMemsetAsync(d_ws, 0, offsetof(WS, uv), stream);
  pack_kernel<<<dim3(1033), dim3(256), 0, stream>>>(Wg, Wt, states, bp, ws);
  vega_kernel<<<dim3(GRID), dim3(NT), 0, stream>>>(
      ids, states, emb, nx_w, nx_b, Wp, bp, ns_w, ns_b,
      W1, b1, W2, b2, on_w, on_b, head_W, head_b, out, ws);
}

// Round 7
// 4421.937 us; speedup vs baseline: 1.0421x; 1.0421x over previous
//
#include <hip/hip_runtime.h>
#include <hip/hip_bf16.h>
#include <math.h>
#include <stddef.h>

namespace {

constexpr int V = 32000, H = 512, L = 4, A = 384, B = 2, T = 32, FF = 2048;
constexpr long LOGITS = (long)B * T * V;   // 2,048,000
constexpr int GRID = 256, NT = 512;
constexpr int NXR = 40;                    // roles (blocks) per x layer-set
constexpr int NGB = 8;                     // ghost blocks per (l,b)
constexpr float EPS = 1e-5f;

typedef short bf16x8 __attribute__((ext_vector_type(8)));
typedef float f32x4 __attribute__((ext_vector_type(4)));

struct WS {
  // ---- zeroed region ----
  unsigned gbar_cnt, gbar_gen;
  unsigned pad0[62];
  unsigned p1c[L], p2c[L], p3c[L];
  unsigned pad1[52];
  unsigned gcol_cnt[L][T][B];
  unsigned pad2[64];
  float gcol[L][T][B][H];          // atomicAdd accumulated
  // ---- not zeroed (fully written before read every launch) ----
  float uv[T][L][B][A + H];        // v part [A..A+H) used on critical path + E1
  float lnxs[T][L][B][H];          // LN1 outputs (for E1 u-reconstruction)
  float outs[T][B][H];
  float lnouts[T * B][H];
  float xn[3][T][B][H];            // layer handoff l -> l+1
  float hbuf[L][2][B][FF];         // t-parity double buffer
  float initcol[L * B * H];
  float bus[4];
  float wU[L][H];                  // column sums of Wp_u
  uint4 bpk[L][2][2][16][32][64];  // ghost bf16 frag-packed W (hi/lo split)
};

union __align__(16) SMem {
  struct { float s[16][516]; uint4 Ahi[16][64]; uint4 Alo[16][64]; } g;   // ~66 KB
  struct {
    unsigned wp[13][256];          // Wp v-rows slice, bf16 pair
    unsigned w1[52][256];          // W1 slice
    unsigned w2[13][1024];         // W2 slice, pair (k, k+1024)
    float xm[2][512];
    float lnx[2][512];
    float h[2][2048];
    float2 red[8];
  } xp;                            // ~141 KB
  struct { float u16[T][16]; float lnx[H]; } e1;
  struct { float tile[125][64]; } hd;
};

__device__ __forceinline__ float dot4(const float4& a, const float4& b) {
  return a.x * b.x + a.y * b.y + a.z * b.z + a.w * b.w;
}
__device__ __forceinline__ unsigned bf16r(float f) {
  unsigned u = __float_as_uint(f);
  return (u + 0x7fffu + ((u >> 16) & 1u)) >> 16;
}
// SYSTEM-scope relaxed = sc0 sc1: uncached, reads/writes the coherence point.
__device__ __forceinline__ float sload(const float* p) {
  return __hip_atomic_load(p, __ATOMIC_RELAXED, __HIP_MEMORY_SCOPE_SYSTEM);
}
__device__ __forceinline__ void sstore(float* p, float v) {
  __hip_atomic_store(p, v, __ATOMIC_RELAXED, __HIP_MEMORY_SCOPE_SYSTEM);
}
__device__ __forceinline__ float2 sload2(const float* p) {
  unsigned long long u = __hip_atomic_load((const unsigned long long*)p,
                                           __ATOMIC_RELAXED, __HIP_MEMORY_SCOPE_SYSTEM);
  return __builtin_bit_cast(float2, u);
}
__device__ __forceinline__ unsigned sload_u(const unsigned* p) {
  return __hip_atomic_load(p, __ATOMIC_RELAXED, __HIP_MEMORY_SCOPE_SYSTEM);
}
__device__ __forceinline__ f32x4 mfma16(bf16x8 a, bf16x8 b, f32x4 c) {
  return __builtin_amdgcn_mfma_f32_16x16x32_bf16(a, b, c, 0, 0, 0);
}

__device__ void wait_u32(unsigned* p, unsigned target) {
  int spin = 0;
  while (__hip_atomic_load(p, __ATOMIC_RELAXED, __HIP_MEMORY_SCOPE_AGENT) < target) {
    __builtin_amdgcn_s_sleep(8);
    if ((++spin & 63) == 0)
      (void)__hip_atomic_load(p, __ATOMIC_ACQUIRE, __HIP_MEMORY_SCOPE_AGENT);
  }
}

__device__ void gbar(WS* ws) {
  __syncthreads();
  if (threadIdx.x == 0) {
    __threadfence();
    unsigned g = __hip_atomic_load(&ws->gbar_gen, __ATOMIC_RELAXED, __HIP_MEMORY_SCOPE_AGENT);
    unsigned a = __hip_atomic_fetch_add(&ws->gbar_cnt, 1u, __ATOMIC_ACQ_REL, __HIP_MEMORY_SCOPE_AGENT);
    if (a == (unsigned)(GRID - 1)) {
      __hip_atomic_store(&ws->gbar_cnt, 0u, __ATOMIC_RELAXED, __HIP_MEMORY_SCOPE_AGENT);
      __hip_atomic_fetch_add(&ws->gbar_gen, 1u, __ATOMIC_RELEASE, __HIP_MEMORY_SCOPE_AGENT);
    } else {
      wait_u32(&ws->gbar_gen, g + 1);
    }
    __threadfence();
  }
  __syncthreads();
}

// ---- counter sync fabric: RMW producers, uncached-load pollers ----
__device__ void cdone(unsigned* p) {
  __builtin_amdgcn_s_waitcnt(0);   // all payload stores globally visible
  __syncthreads();                 // all waves done
  if (threadIdx.x == 0)
    __hip_atomic_fetch_add(p, 1u, __ATOMIC_RELAXED, __HIP_MEMORY_SCOPE_AGENT);
}
__device__ void cwait(unsigned* p, unsigned tgt) {
  if (threadIdx.x == 0) {
    int spin = 0;
    while (sload_u(p) < tgt) {
      __builtin_amdgcn_s_sleep(2);
      if ((++spin & 1023) == 0)  // backstop; ~never fires
        (void)__hip_atomic_load(p, __ATOMIC_ACQUIRE, __HIP_MEMORY_SCOPE_AGENT);
    }
  }
  __syncthreads();
}
__device__ void cwait3(unsigned* pa, unsigned ta, unsigned* pb, unsigned tbv,
                       unsigned* pc, unsigned tcv) {
  if (threadIdx.x < 64) {
    unsigned* p = pa;
    unsigned tg = ta;
    if (threadIdx.x == 1) { p = pb; tg = tbv; }
    if (threadIdx.x == 2) { p = pc; tg = tcv; }
    const bool act = threadIdx.x < 3;
    int spin = 0;
    for (;;) {
      bool ok = !act || sload_u(p) >= tg;
      if (__all(ok)) break;
      __builtin_amdgcn_s_sleep(2);
      if ((++spin & 1023) == 0 && act)
        (void)__hip_atomic_load(p, __ATOMIC_ACQUIRE, __HIP_MEMORY_SCOPE_AGENT);
    }
  }
  __syncthreads();
}

__device__ float2 wred2(float2 v) {
  #pragma unroll
  for (int off = 1; off < 64; off <<= 1) {
    v.x += __shfl_xor(v.x, off);
    v.y += __shfl_xor(v.y, off);
  }
  return v;
}

__device__ float2 block_red2(float2 v, SMem& sm) {
  v = wred2(v);
  int w = threadIdx.x >> 6;
  __syncthreads();
  if ((threadIdx.x & 63) == 0) sm.xp.red[w] = v;
  __syncthreads();
  float2 s{0.f, 0.f};
  #pragma unroll
  for (int q = 0; q < 8; ++q) { s.x += sm.xp.red[q].x; s.y += sm.xp.red[q].y; }
  return s;
}

__device__ void ln512(SMem& sm, const float* in, float* outp,
                      const float* w, const float* b) {
  int tid = threadIdx.x;
  float xv = in[tid];
  float m = block_red2({xv, 0.f}, sm).x * (1.f / H);
  float d = xv - m;
  float var = block_red2({d * d, 0.f}, sm).x * (1.f / H);
  float inv = rsqrtf(var + EPS);
  outp[tid] = d * inv * w[tid] + b[tid];
  __syncthreads();
}

__device__ void ln2pair(SMem& sm, const float* w, const float* b) {
  int tid = threadIdx.x;
  float x0 = sm.xp.xm[0][tid], x1 = sm.xp.xm[1][tid];
  float2 mm = block_red2({x0, x1}, sm);
  float d0 = x0 - mm.x * (1.f / H), d1 = x1 - mm.y * (1.f / H);
  float2 vv = block_red2({d0 * d0, d1 * d1}, sm);
  float i0 = rsqrtf(vv.x * (1.f / H) + EPS), i1 = rsqrtf(vv.y * (1.f / H) + EPS);
  float wv_ = w[tid], bv = b[tid];
  sm.xp.lnx[0][tid] = d0 * i0 * wv_ + bv;
  sm.xp.lnx[1][tid] = d1 * i1 * wv_ + bv;
  __syncthreads();
}

__device__ __forceinline__ float2 d8(uint4 wq, const float* xr0, const float* xr1) {
  float2 a{0.f, 0.f};
  unsigned u[4] = {wq.x, wq.y, wq.z, wq.w};
  #pragma unroll
  for (int j = 0; j < 4; ++j) {
    float wl = __uint_as_float(u[j] << 16);
    float wh = __uint_as_float(u[j] & 0xffff0000u);
    a.x = fmaf(wl, xr0[2 * j], fmaf(wh, xr0[2 * j + 1], a.x));
    a.y = fmaf(wl, xr1[2 * j], fmaf(wh, xr1[2 * j + 1], a.y));
  }
  return a;
}

// ---------------------------------------------------------------- ghost (MFMA)
__device__ void ghost_mfma(int l, int b, int r0, WS* ws, SMem& sm,
                           const float* __restrict__ states, float* __restrict__ fs) {
  const int tid = threadIdx.x, wv = tid >> 6, lane = tid & 63;
  for (int i = tid; i < 16 * 512; i += NT) {
    int r = i >> 9, k = i & 511;
    sm.g.s[r][k] = states[((((long)l * B + b) * H) + A + r0 + r) * H + k];
  }
  __syncthreads();
  const int ct0 = wv * 4;

  for (int rec = 0; rec < 2 * T; ++rec) {
    for (int q = tid; q < 1024; q += NT) {
      int kt = q >> 6, ln = q & 63;
      int row = ln & 15, kb = kt * 32 + ((ln >> 4) << 3);
      unsigned h[8], lo[8];
      #pragma unroll
      for (int j = 0; j < 8; ++j) {
        float v = sm.g.s[row][kb + j];
        h[j] = bf16r(v);
        float hf = __uint_as_float(h[j] << 16);
        lo[j] = bf16r(v - hf);
      }
      uint4 uh, ul;
      uh.x = h[0] | (h[1] << 16);  uh.y = h[2] | (h[3] << 16);
      uh.z = h[4] | (h[5] << 16);  uh.w = h[6] | (h[7] << 16);
      ul.x = lo[0] | (lo[1] << 16); ul.y = lo[2] | (lo[3] << 16);
      ul.z = lo[4] | (lo[5] << 16); ul.w = lo[6] | (lo[7] << 16);
      sm.g.Ahi[kt][ln] = uh;
      sm.g.Alo[kt][ln] = ul;
    }
    __syncthreads();

    f32x4 accg[4], acct[4];
    #pragma unroll
    for (int c = 0; c < 4; ++c) { accg[c] = {0.f, 0.f, 0.f, 0.f}; acct[c] = {0.f, 0.f, 0.f, 0.f}; }
    for (int kt = 0; kt < 16; ++kt) {
      bf16x8 ahi = __builtin_bit_cast(bf16x8, sm.g.Ahi[kt][lane]);
      bf16x8 alo = __builtin_bit_cast(bf16x8, sm.g.Alo[kt][lane]);
      #pragma unroll
      for (int c = 0; c < 4; ++c) {
        int ct = ct0 + c;
        bf16x8 bgh = __builtin_bit_cast(bf16x8, ws->bpk[l][0][0][kt][ct][lane]);
        bf16x8 bgl = __builtin_bit_cast(bf16x8, ws->bpk[l][0][1][kt][ct][lane]);
        bf16x8 bth = __builtin_bit_cast(bf16x8, ws->bpk[l][1][0][kt][ct][lane]);
        bf16x8 btl = __builtin_bit_cast(bf16x8, ws->bpk[l][1][1][kt][ct][lane]);
        accg[c] = mfma16(ahi, bgh, accg[c]);
        accg[c] = mfma16(ahi, bgl, accg[c]);
        accg[c] = mfma16(alo, bgh, accg[c]);
        acct[c] = mfma16(ahi, bth, acct[c]);
        acct[c] = mfma16(ahi, btl, acct[c]);
        acct[c] = mfma16(alo, bth, acct[c]);
      }
    }

    const int t = rec >> 1;
    const bool pub = (rec & 1) != 0;
    const int rb = (lane >> 4) * 4;
    #pragma unroll
    for (int c = 0; c < 4; ++c) {
      int col = (ct0 + c) * 16 + (lane & 15);
      float cs = 0.f;
      #pragma unroll
      for (int r = 0; r < 4; ++r) {
        float sig = 1.f / (1.f + expf(-accg[c][r]));
        float th = tanhf(acct[c][r]);
        float nv = sm.g.s[rb + r][col] + sig * th;
        sm.g.s[rb + r][col] = nv;
        cs += nv;
      }
      if (pub) {
        cs += __shfl_xor(cs, 16);
        cs += __shfl_xor(cs, 32);
        if (lane < 16)
          __hip_atomic_fetch_add(&ws->gcol[l][t][b][col], cs,
                                 __ATOMIC_RELAXED, __HIP_MEMORY_SCOPE_AGENT);
      }
    }
    if (pub) {
      __builtin_amdgcn_s_waitcnt(0);
      __syncthreads();
      if (tid == 0)
        __hip_atomic_fetch_add(&ws->gcol_cnt[l][t][b], 1u,
                               __ATOMIC_RELAXED, __HIP_MEMORY_SCOPE_AGENT);
    } else {
      __syncthreads();
    }
  }
  for (int i = tid; i < 16 * 512; i += NT) {
    int r = i >> 9, k = i & 511;
    fs[((((long)l * B + b) * H) + A + r0 + r) * H + k] = sm.g.s[r][k];
  }
}

// ---------------------------------------------------------------- x layer-set
__device__ void x_set(int l, int role, WS* ws, SMem& sm,
                      const int* ids, const float* emb,
                      const float* nx_w, const float* nx_b,
                      const float* Wp, const float* bp,
                      const float* ns_w, const float* ns_b,
                      const float* W1, const float* b1,
                      const float* W2, const float* b2) {
  const int tid = threadIdx.x, wv = tid >> 6, lane = tid & 63;
  const long wb = (long)l * (A + H);
  const int v0r = (role * 512) / NXR,  v1r = ((role + 1) * 512) / NXR;
  const int a0 = (role * 2048) / NXR, a1 = ((role + 1) * 2048) / NXR;
  const int c0 = (role * 512) / NXR,  c1 = ((role + 1) * 512) / NXR;

  // ---- one-time: weight slices -> LDS (bf16-packed) ----
  for (int i = tid; i < (v1r - v0r) * 256; i += NT) {
    int row = i >> 8, m = i & 255;
    const float* s = Wp + (wb + A + v0r + row) * H + 2 * m;
    sm.xp.wp[row][m] = bf16r(s[0]) | (bf16r(s[1]) << 16);
  }
  for (int i = tid; i < (a1 - a0) * 256; i += NT) {
    int row = i >> 8, m = i & 255;
    const float* s = W1 + ((long)l * FF + a0 + row) * H + 2 * m;
    sm.xp.w1[row][m] = bf16r(s[0]) | (bf16r(s[1]) << 16);
  }
  for (int i = tid; i < (c1 - c0) * 1024; i += NT) {
    int row = i >> 10, q = i & 1023;
    const float* s = W2 + ((long)l * H + c0 + row) * FF + q;
    sm.xp.w2[row][q] = bf16r(s[0]) | (bf16r(s[1024]) << 16);
  }
  const float ic0 = ws->initcol[(l * B + 0) * H + tid];
  const float ic1 = ws->initcol[(l * B + 1) * H + tid];
  const float BU = ws->bus[l];
  const float bpA = bp[wb + A + tid];
  const float wU0 = ws->wU[l][tid];
  float as0 = 0.f, as1 = 0.f;
  __syncthreads();

  for (int t = 0; t < T; ++t) {
    // ---- P0: x input ----
    if (l == 0) {
      sm.xp.xm[0][tid] = emb[(long)ids[t] * H + tid];
      sm.xp.xm[1][tid] = emb[(long)ids[T + t] * H + tid];
    } else {
      cwait(&ws->p3c[l - 1], (unsigned)(NXR * (t + 1)));
      sm.xp.xm[0][tid] = sload(&ws->xn[l - 1][t][0][tid]);
      sm.xp.xm[1][tid] = sload(&ws->xn[l - 1][t][1][tid]);
    }
    __syncthreads();
    // ---- P1: LN1 + v-slice + lnx publish ----
    ln2pair(sm, nx_w + l * H, nx_b + l * H);
    float xr0[8], xr1[8];
    #pragma unroll
    for (int j = 0; j < 8; ++j) {
      xr0[j] = sm.xp.lnx[0][lane * 8 + j];
      xr1[j] = sm.xp.lnx[1][lane * 8 + j];
    }
    for (int row = v0r + wv; row < v1r; row += 8) {
      uint4 wq = *(const uint4*)&sm.xp.wp[row - v0r][lane * 4];
      float2 acc = wred2(d8(wq, xr0, xr1));
      if (lane == 0) {
        float bb = bp[wb + A + row];
        sstore(&ws->uv[t][l][0][A + row], acc.x + bb);
        sstore(&ws->uv[t][l][1][A + row], acc.y + bb);
      }
    }
    if (tid >= v0r && tid < v1r) {
      sstore(&ws->lnxs[t][l][0][tid], sm.xp.lnx[0][tid]);
      sstore(&ws->lnxs[t][l][1][tid], sm.xp.lnx[1][tid]);
    }
    cdone(&ws->p1c[l]);
    // U1 locally from wU (uses LN1 lnx, before overwrite)
    float2 ul{wU0 * sm.xp.lnx[0][tid], wU0 * sm.xp.lnx[1][tid]};
    float2 U1 = block_red2(ul, sm);
    cwait3(&ws->p1c[l], (unsigned)(NXR * (t + 1)),
           &ws->gcol_cnt[l][t][0], NGB, &ws->gcol_cnt[l][t][1], NGB);
    // ---- P2: asum, xm, LN2, W1 slice ----
    float v0 = sload(&ws->uv[t][l][0][A + tid]);
    float v1 = sload(&ws->uv[t][l][1][A + tid]);
    float gc0 = sload(&ws->gcol[l][t][0][tid]);
    float gc1 = sload(&ws->gcol[l][t][1][tid]);
    as0 += (U1.x + BU) * v0;
    as1 += (U1.y + BU) * v1;
    float tb = (float)(t + 1) * BU * bpA;
    sm.xp.xm[0][tid] += (as0 + ic0 + tb + gc0) * (1.f / H);
    sm.xp.xm[1][tid] += (as1 + ic1 + tb + gc1) * (1.f / H);
    ln2pair(sm, ns_w + l * H, ns_b + l * H);
    #pragma unroll
    for (int j = 0; j < 8; ++j) {
      xr0[j] = sm.xp.lnx[0][lane * 8 + j];
      xr1[j] = sm.xp.lnx[1][lane * 8 + j];
    }
    for (int row = a0 + wv; row < a1; row += 8) {
      uint4 wq = *(const uint4*)&sm.xp.w1[row - a0][lane * 4];
      float2 acc = wred2(d8(wq, xr0, xr1));
      if (lane == 0) {
        float bb = b1[(long)l * FF + row];
        float z0 = acc.x + bb, z1 = acc.y + bb;
        sstore(&ws->hbuf[l][t & 1][0][row], 0.5f * z0 * (1.f + erff(z0 * 0.70710678118f)));
        sstore(&ws->hbuf[l][t & 1][1][row], 0.5f * z1 * (1.f + erff(z1 * 0.70710678118f)));
      }
    }
    cdone(&ws->p2c[l]);
    cwait(&ws->p2c[l], (unsigned)(NXR * (t + 1)));
    // ---- P3: gather h, W2 slice, residual, publish ----
    for (int pidx = tid; pidx < 2048; pidx += NT) {
      int b = pidx >> 10, m = pidx & 1023;
      float2 hv = sload2(&ws->hbuf[l][t & 1][b][2 * m]);
      *(float2*)&sm.xp.h[b][2 * m] = hv;
    }
    __syncthreads();
    for (int row = c0 + wv; row < c1; row += 8) {
      float2 acc{0.f, 0.f};
      #pragma unroll
      for (int qq = 0; qq < 16; ++qq) {
        unsigned w = sm.xp.w2[row - c0][qq * 64 + lane];
        float wl = __uint_as_float(w << 16);
        float wh = __uint_as_float(w & 0xffff0000u);
        int k = qq * 64 + lane;
        acc.x += wl * sm.xp.h[0][k] + wh * sm.xp.h[0][k + 1024];
        acc.y += wl * sm.xp.h[1][k] + wh * sm.xp.h[1][k + 1024];
      }
      acc = wred2(acc);
      if (lane == 0) {
        float bb = b2[(long)l * H + row];
        float o0 = sm.xp.xm[0][row] + acc.x + bb;
        float o1 = sm.xp.xm[1][row] + acc.y + bb;
        if (l == L - 1) {
          sstore(&ws->outs[t][0][row], o0);
          sstore(&ws->outs[t][1][row], o1);
        } else {
          sstore(&ws->xn[l][t][0][row], o0);
          sstore(&ws->xn[l][t][1][row], o1);
        }
      }
    }
    cdone(&ws->p3c[l]);
  }
}

// ---------------------------------------------------------------- prologue pack
__global__ __launch_bounds__(256) void pack_kernel(const float* __restrict__ Wg,
                                                   const float* __restrict__ Wt,
                                                   const float* __restrict__ states,
                                                   const float* __restrict__ bp,
                                                   const float* __restrict__ Wp,
                                                   WS* ws) {
  const int bid = blockIdx.x, tid = threadIdx.x;
  if (bid < 1024) {
    #pragma unroll
    for (int rep = 0; rep < 2; ++rep) {
      unsigned f = (unsigned)bid * 512u + (unsigned)rep * 256u + (unsigned)tid;
      int lane = f & 63, ct = (f >> 6) & 31, kt = (f >> 11) & 15;
      int split = (f >> 15) & 1, mat = (f >> 16) & 1, l = f >> 17;
      int o = ct * 16 + (lane & 15), kb = kt * 32 + ((lane >> 4) << 3);
      const float* src = (mat ? Wt : Wg) + ((long)l * H + o) * H + kb;
      unsigned v8[8];
      #pragma unroll
      for (int j = 0; j < 8; ++j) {
        float w = src[j];
        unsigned h = bf16r(w);
        if (split) {
          float hf = __uint_as_float(h << 16);
          h = bf16r(w - hf);
        }
        v8[j] = h;
      }
      uint4 u;
      u.x = v8[0] | (v8[1] << 16); u.y = v8[2] | (v8[3] << 16);
      u.z = v8[4] | (v8[5] << 16); u.w = v8[6] | (v8[7] << 16);
      ws->bpk[l][mat][split][kt][ct][lane] = u;
    }
  } else if (bid < 1032) {
    int lb = bid - 1024, l = lb >> 1, b = lb & 1;
    #pragma unroll
    for (int half = 0; half < 2; ++half) {
      int col = tid + half * 256;
      float acc = 0.f;
      for (int i = 0; i < A; ++i)
        acc += states[(((long)l * B + b) * H + i) * H + col];
      ws->initcol[(l * B + b) * H + col] = acc;
    }
  } else if (bid == 1032) {
    __shared__ float tmp[256];
    int l = tid >> 6, i = tid & 63;
    float p = 0.f;
    for (int j = 0; j < 6; ++j) p += bp[(long)l * (A + H) + j * 64 + i];
    tmp[tid] = p;
    __syncthreads();
    if (tid < 4) {
      float s = 0.f;
      for (int q = 0; q < 64; ++q) s += tmp[tid * 64 + q];
      ws->bus[tid] = s;
    }
  } else {
    int l = bid - 1033;  // wU[l][k] = sum_{i<A} Wp[l][i][k]
    #pragma unroll
    for (int half = 0; half < 2; ++half) {
      int k = tid + half * 256;
      float acc = 0.f;
      for (int i = 0; i < A; ++i)
        acc += Wp[((long)l * (A + H) + i) * H + k];
      ws->wU[l][k] = acc;
    }
  }
}

// ---------------------------------------------------------------- main kernel
__global__ __launch_bounds__(NT, 1) void vega_kernel(
    const int* __restrict__ ids, const float* __restrict__ states,
    const float* __restrict__ emb,
    const float* __restrict__ nx_w, const float* __restrict__ nx_b,
    const float* __restrict__ Wp, const float* __restrict__ bp,
    const float* __restrict__ ns_w, const float* __restrict__ ns_b,
    const float* __restrict__ W1, const float* __restrict__ b1,
    const float* __restrict__ W2, const float* __restrict__ b2,
    const float* __restrict__ on_w, const float* __restrict__ on_b,
    const float* __restrict__ head_W, const float* __restrict__ head_b,
    float* __restrict__ out, WS* ws) {
  __shared__ SMem sm;
  const int bid = blockIdx.x, tid = threadIdx.x;
  float* fs = out + LOGITS;

  const int c = bid & 7, j = bid >> 3;
  if (c < 4 && j < 16) {
    ghost_mfma(c, j >> 3, (j & 7) * 16, ws, sm, states, fs);
  } else if (c >= 4) {
    x_set(c - 4, j, ws, sm, ids, emb, nx_w, nx_b, Wp, bp,
          ns_w, ns_b, W1, b1, W2, b2);
  } else if (j < 24) {
    x_set(c, 32 + (j - 16), ws, sm, ids, emb, nx_w, nx_b, Wp, bp,
          ns_w, ns_b, W1, b1, W2, b2);
  }
  // remaining 32 blocks idle until epilogue

  gbar(ws);

  // -------- E1: fstates reconstruction (u from lnx) + final LN of outs --------
  if (bid < 192) {
    int lb = bid / 24, sub = bid % 24;
    int l = lb >> 1, b = lb & 1, r0 = sub * 16;
    const long wb = (long)l * (A + H);
    const int row = tid >> 5, kc = tid & 31;
    float wreg[16];
    {
      const float* wr = Wp + (wb + r0 + row) * H + kc * 16;
      #pragma unroll
      for (int jj = 0; jj < 16; ++jj) wreg[jj] = wr[jj];
    }
    const float bprow = bp[wb + r0 + row];
    float pre = sload(&ws->lnxs[0][l][b][tid]);
    for (int t2 = 0; t2 < T; ++t2) {
      sm.e1.lnx[tid] = pre;
      __syncthreads();
      if (t2 + 1 < T) pre = sload(&ws->lnxs[t2 + 1][l][b][tid]);
      float part = 0.f;
      #pragma unroll
      for (int jj = 0; jj < 16; ++jj) part += wreg[jj] * sm.e1.lnx[kc * 16 + jj];
      #pragma unroll
      for (int off = 1; off < 32; off <<= 1) part += __shfl_xor(part, off);
      if (kc == 0) sm.e1.u16[t2][row] = part + bprow;
      __syncthreads();
    }
    float bv = bp[wb + A + tid];
    float acc[16];
    #pragma unroll
    for (int q = 0; q < 16; ++q) acc[q] = 32.f * bp[wb + r0 + q] * bv;
    for (int t2 = 0; t2 < T; ++t2) {
      float vv = sload(&ws->uv[t2][l][b][A + tid]);
      #pragma unroll
      for (int q = 0; q < 16; ++q) acc[q] = fmaf(sm.e1.u16[t2][q], vv, acc[q]);
    }
    #pragma unroll
    for (int q = 0; q < 16; ++q)
      fs[(((long)l * B + b) * H + (r0 + q)) * H + tid] =
          states[(((long)l * B + b) * H + (r0 + q)) * H + tid] + acc[q];
  }
  if (bid < T * B) {
    int row = bid, t = row >> 1, b = row & 1;
    ln512(sm, ws->outs[t][b], ws->lnouts[row], on_w, on_b);
  }

  gbar(ws);

  // -------- E2: head GEMM (64 rows x 125 vocab per block, K=512) --------
  {
    const int wv = tid >> 6, lane = tid & 63;
    const long vbase = (long)bid * 125;
    float acc[16];
    #pragma unroll
    for (int q = 0; q < 16; ++q) acc[q] = 0.f;
    for (int cc = 0; cc < 8; ++cc) {
      float4 xr[16];
      #pragma unroll
      for (int q = 0; q < 16; ++q)
        xr[q] = *(const float4*)&ws->lnouts[lane][cc * 64 + q * 4];
      #pragma unroll
      for (int vi = 0; vi < 16; ++vi) {
        int vloc = vi * 8 + wv;
        if (vloc < 125) {
          const float4* wp_ = (const float4*)(head_W + (vbase + vloc) * H + cc * 64);
          float s = 0.f;
          #pragma unroll
          for (int q = 0; q < 16; ++q) s += dot4(xr[q], wp_[q]);
          acc[vi] += s;
        }
      }
    }
    #pragma unroll
    for (int vi = 0; vi < 16; ++vi) {
      int vloc = vi * 8 + wv;
      if (vloc < 125) sm.hd.tile[vloc][lane] = acc[vi] + head_b[vbase + vloc];
    }
    __syncthreads();
    for (int idx = tid; idx < 64 * 125; idx += NT) {
      int row = idx / 125, vl = idx % 125;
      int t = row >> 1, b = row & 1;
      out[((long)(b * T + t)) * V + vbase + vl] = sm.hd.tile[vl][row];
    }
  }
}

}  // namespace

extern "C" void kernel_launch(void* const* d_in, const int* in_sizes, int n_in,
                              void* d_out, int out_size, void* d_ws, size_t ws_size,
                              hipStream_t stream) {
  (void)in_sizes; (void)n_in; (void)out_size; (void)ws_size;
  const int*   ids    = (const int*)d_in[0];
  const float* states = (const float*)d_in[1];
  const float* emb    = (const float*)d_in[2];
  const float* nx_w   = (const float*)d_in[3];
  const float* nx_b   = (const float*)d_in[4];
  const float* Wp     = (const float*)d_in[5];
  const float* bp     = (const float*)d_in[6];
  const float* Wg     = (const float*)d_in[7];
  const float* Wt     = (const float*)d_in[8];
  const float* ns_w   = (const float*)d_in[9];
  const float* ns_b   = (const float*)d_in[10];
  const float* W1     = (const float*)d_in[11];
  const float* b1     = (const float*)d_in[12];
  const float* W2     = (const float*)d_in[13];
  const float* b2     = (const float*)d_in[14];
  const float* on_w   = (const float*)d_in[15];
  const float* on_b   = (const float*)d_in[16];
  const float* head_W = (const float*)d_in[17];
  const float* head_b = (const float*)d_in[18];
  float* out = (float*)d_out;
  WS* ws = (WS*)d_ws;

  hipMemsetAsync(d_ws, 0, offsetof(WS, uv), stream);
  pack_kernel<<<dim3(1037), dim3(256), 0, stream>>>(Wg, Wt, states, bp, Wp, ws);
  vega_kernel<<<dim3(GRID), dim3(NT), 0, stream>>>(
      ids, states, emb, nx_w, nx_b, Wp, bp, ns_w, ns_b,
      W1, b1, W2, b2, on_w, on_b, head_W, head_b, out, ws);
}

// Round 9
// 2924.680 us; speedup vs baseline: 1.5756x; 1.5119x over previous
//
#include <hip/hip_runtime.h>
#include <hip/hip_bf16.h>
#include <math.h>
#include <stddef.h>

namespace {

constexpr int V = 32000, H = 512, L = 4, A = 384, B = 2, T = 32, FF = 2048;
constexpr long LOGITS = (long)B * T * V;   // 2,048,000
constexpr int GRID = 256, NT = 512;
constexpr int NXR = 32;                    // x roles per layer
constexpr int NGB = 32;                    // ghost blocks per layer (col-sliced)
constexpr float EPS = 1e-5f;

typedef short bf16x8 __attribute__((ext_vector_type(8)));
typedef float f32x4 __attribute__((ext_vector_type(4)));

struct WS {
  // ---- zeroed region ----
  unsigned gbar_cnt, gbar_gen;
  unsigned pad0[62];
  unsigned p1c[L], p2c[L], p3c[L], grc[L];
  unsigned pad1[48];
  unsigned gcol_cnt2[L][T];
  unsigned pad2[64];
  float gcol[L][T][B][H];
  // ---- not zeroed (fully written before read every launch) ----
  float uv[T][L][B][A + H];
  float lnxs[T][L][B][H];
  float outs[T][B][H];
  float lnouts[T * B][H];
  float xn[3][T][B][H];
  float hbuf[L][2][B][FF];
  float initcol[L * B * H];
  float bus[4];
  float wU[L][H];
  uint4 bpk[L][2][2][16][32][64];                 // ghost W frag-packed (hi/lo split)
  unsigned long long afr[L][2][2][2][8][16][64][2]; // A-frag exchange [l][pp][b][split][rt][kt][lane][half]
};

union __align__(16) SMem {
  struct { unsigned xch[8][2][16][16]; float colp[8][2][16]; } gx;  // 17 KB (ghost)
  struct {
    unsigned wp[16][256];   // 16 KB  Wp v-rows, bf16 pair (2m,2m+1)
    unsigned w1[64][256];   // 64 KB
    unsigned w2[16][1024];  // 64 KB  pair (2m,2m+1)
    float lnx[2][512];      // 4 KB
    unsigned hb[2][1024];   // 8 KB   h as bf16 pairs
    float xms[2][16];
    float2 red[8];
  } xp;                     // ~156 KB
  struct { float u16[T][16]; float lnx[H]; } e1;
  struct { float tile[125][64]; } hd;
};

__device__ __forceinline__ float dot4(const float4& a, const float4& b) {
  return a.x * b.x + a.y * b.y + a.z * b.z + a.w * b.w;
}
__device__ __forceinline__ unsigned bf16r(float f) {
  unsigned u = __float_as_uint(f);
  return (u + 0x7fffu + ((u >> 16) & 1u)) >> 16;
}
// system-scope relaxed: uncached, coherence-point reads/writes (proven r7 fabric)
__device__ __forceinline__ float sload(const float* p) {
  return __hip_atomic_load(p, __ATOMIC_RELAXED, __HIP_MEMORY_SCOPE_SYSTEM);
}
__device__ __forceinline__ void sstore(float* p, float v) {
  __hip_atomic_store(p, v, __ATOMIC_RELAXED, __HIP_MEMORY_SCOPE_SYSTEM);
}
__device__ __forceinline__ unsigned long long sld64(const unsigned long long* p) {
  return __hip_atomic_load(p, __ATOMIC_RELAXED, __HIP_MEMORY_SCOPE_SYSTEM);
}
__device__ __forceinline__ void sst64(unsigned long long* p, unsigned long long v) {
  __hip_atomic_store(p, v, __ATOMIC_RELAXED, __HIP_MEMORY_SCOPE_SYSTEM);
}
__device__ __forceinline__ unsigned sload_u(const unsigned* p) {
  return __hip_atomic_load(p, __ATOMIC_RELAXED, __HIP_MEMORY_SCOPE_SYSTEM);
}
__device__ __forceinline__ f32x4 mfma16(bf16x8 a, bf16x8 b, f32x4 c) {
  return __builtin_amdgcn_mfma_f32_16x16x32_bf16(a, b, c, 0, 0, 0);
}
__device__ __forceinline__ bf16x8 bc2(unsigned long long a, unsigned long long b) {
  ulonglong2 t{a, b};
  return __builtin_bit_cast(bf16x8, t);
}
__device__ __forceinline__ bf16x8 bcu4(uint4 u) {
  return __builtin_bit_cast(bf16x8, u);
}

__device__ void wait_u32(unsigned* p, unsigned target) {
  int spin = 0;
  while (__hip_atomic_load(p, __ATOMIC_RELAXED, __HIP_MEMORY_SCOPE_AGENT) < target) {
    __builtin_amdgcn_s_sleep(8);
    if ((++spin & 63) == 0)
      (void)__hip_atomic_load(p, __ATOMIC_ACQUIRE, __HIP_MEMORY_SCOPE_AGENT);
  }
}

__device__ void gbar(WS* ws) {
  __syncthreads();
  if (threadIdx.x == 0) {
    __threadfence();
    unsigned g = __hip_atomic_load(&ws->gbar_gen, __ATOMIC_RELAXED, __HIP_MEMORY_SCOPE_AGENT);
    unsigned a = __hip_atomic_fetch_add(&ws->gbar_cnt, 1u, __ATOMIC_ACQ_REL, __HIP_MEMORY_SCOPE_AGENT);
    if (a == (unsigned)(GRID - 1)) {
      __hip_atomic_store(&ws->gbar_cnt, 0u, __ATOMIC_RELAXED, __HIP_MEMORY_SCOPE_AGENT);
      __hip_atomic_fetch_add(&ws->gbar_gen, 1u, __ATOMIC_RELEASE, __HIP_MEMORY_SCOPE_AGENT);
    } else {
      wait_u32(&ws->gbar_gen, g + 1);
    }
    __threadfence();
  }
  __syncthreads();
}

__device__ void cdone(unsigned* p) {
  __builtin_amdgcn_s_waitcnt(0);
  __syncthreads();
  if (threadIdx.x == 0)
    __hip_atomic_fetch_add(p, 1u, __ATOMIC_RELAXED, __HIP_MEMORY_SCOPE_AGENT);
}
__device__ void cwait(unsigned* p, unsigned tgt) {
  if (threadIdx.x == 0) {
    int spin = 0;
    while (sload_u(p) < tgt) {
      __builtin_amdgcn_s_sleep(2);
      if ((++spin & 1023) == 0)
        (void)__hip_atomic_load(p, __ATOMIC_ACQUIRE, __HIP_MEMORY_SCOPE_AGENT);
    }
  }
  __syncthreads();
}
__device__ void cwait2(unsigned* pa, unsigned ta, unsigned* pb, unsigned tbv) {
  if (threadIdx.x < 64) {
    unsigned* p = pa;
    unsigned tg = ta;
    if (threadIdx.x == 1) { p = pb; tg = tbv; }
    const bool act = threadIdx.x < 2;
    int spin = 0;
    for (;;) {
      bool ok = !act || sload_u(p) >= tg;
      if (__all(ok)) break;
      __builtin_amdgcn_s_sleep(2);
      if ((++spin & 1023) == 0 && act)
        (void)__hip_atomic_load(p, __ATOMIC_ACQUIRE, __HIP_MEMORY_SCOPE_AGENT);
    }
  }
  __syncthreads();
}

__device__ float2 wred2(float2 v) {
  #pragma unroll
  for (int off = 1; off < 64; off <<= 1) {
    v.x += __shfl_xor(v.x, off);
    v.y += __shfl_xor(v.y, off);
  }
  return v;
}

__device__ float2 block_red2(float2 v, SMem& sm) {
  v = wred2(v);
  int w = threadIdx.x >> 6;
  __syncthreads();
  if ((threadIdx.x & 63) == 0) sm.xp.red[w] = v;
  __syncthreads();
  float2 s{0.f, 0.f};
  #pragma unroll
  for (int q = 0; q < 8; ++q) { s.x += sm.xp.red[q].x; s.y += sm.xp.red[q].y; }
  return s;
}

__device__ void ln512(SMem& sm, const float* in, float* outp,
                      const float* w, const float* b) {
  int tid = threadIdx.x;
  float xv = in[tid];
  float m = block_red2({xv, 0.f}, sm).x * (1.f / H);
  float d = xv - m;
  float var = block_red2({d * d, 0.f}, sm).x * (1.f / H);
  float inv = rsqrtf(var + EPS);
  outp[tid] = d * inv * w[tid] + b[tid];
  __syncthreads();
}

// dual-batch LN: reg in, LDS lnx + reg out
__device__ float2 ln2reg(SMem& sm, float x0, float x1, const float* w, const float* b) {
  int tid = threadIdx.x;
  float2 mm = block_red2({x0, x1}, sm);
  float d0 = x0 - mm.x * (1.f / H), d1 = x1 - mm.y * (1.f / H);
  float2 vv = block_red2({d0 * d0, d1 * d1}, sm);
  float i0 = rsqrtf(vv.x * (1.f / H) + EPS), i1 = rsqrtf(vv.y * (1.f / H) + EPS);
  float wv_ = w[tid], bv = b[tid];
  float l0 = d0 * i0 * wv_ + bv, l1 = d1 * i1 * wv_ + bv;
  sm.xp.lnx[0][tid] = l0;
  sm.xp.lnx[1][tid] = l1;
  __syncthreads();
  return {l0, l1};
}

__device__ __forceinline__ float2 d8(uint4 wq, const float* xr0, const float* xr1) {
  float2 a{0.f, 0.f};
  unsigned u[4] = {wq.x, wq.y, wq.z, wq.w};
  #pragma unroll
  for (int j = 0; j < 4; ++j) {
    float wl = __uint_as_float(u[j] << 16);
    float wh = __uint_as_float(u[j] & 0xffff0000u);
    a.x = fmaf(wl, xr0[2 * j], fmaf(wh, xr0[2 * j + 1], a.x));
    a.y = fmaf(wl, xr1[2 * j], fmaf(wh, xr1[2 * j + 1], a.y));
  }
  return a;
}

// ------------------------------------------------------- ghost (weights in VGPRs)
__device__ void ghost_regs(int l, int ct, WS* ws, SMem& sm,
                           const float* __restrict__ states, float* __restrict__ fs) {
  const int tid = threadIdx.x, wv = tid >> 6, lane = tid & 63;
  const int c15 = lane & 15, lq = lane >> 4;
  // weight slice -> registers (loaded once; 64 bf16x8/lane)
  bf16x8 wgh[16], wgl[16], wth[16], wtl[16];
  #pragma unroll
  for (int kt = 0; kt < 16; ++kt) {
    wgh[kt] = bcu4(ws->bpk[l][0][0][kt][ct][lane]);
    wgl[kt] = bcu4(ws->bpk[l][0][1][kt][ct][lane]);
    wth[kt] = bcu4(ws->bpk[l][1][0][kt][ct][lane]);
    wtl[kt] = bcu4(ws->bpk[l][1][1][kt][ct][lane]);
  }
  // master state in regs: lane owns rows 16*wv+4*lq+r, col 16*ct+c15, both b
  float ms[2][4];
  #pragma unroll
  for (int b = 0; b < 2; ++b)
    #pragma unroll
    for (int r = 0; r < 4; ++r)
      ms[b][r] = states[((((long)l * B + b) * H) + A + 16 * wv + 4 * lq + r) * H + 16 * ct + c15];

  const int ktp = ct >> 1;
  const int lt_base = 16 * ((ct & 1) * 2);

  #pragma unroll 1
  for (int rec = 0; rec < 2 * T; ++rec) {
    const int pp = rec & 1, np = pp ^ 1;
    f32x4 accg[2], acct[2];
    #pragma unroll
    for (int b = 0; b < 2; ++b) { accg[b] = {0.f,0.f,0.f,0.f}; acct[b] = {0.f,0.f,0.f,0.f}; }
    // 4-deep A-fragment pipeline (uncached 8B loads)
    unsigned long long pf[4][8];
    #pragma unroll
    for (int k0 = 0; k0 < 4; ++k0)
      #pragma unroll
      for (int q = 0; q < 8; ++q)
        pf[k0][q] = sld64(&ws->afr[l][pp][q >> 2][(q >> 1) & 1][wv][k0][lane][q & 1]);
    #pragma unroll
    for (int kt = 0; kt < 16; ++kt) {
      const int sl = kt & 3;
      bf16x8 a00 = bc2(pf[sl][0], pf[sl][1]);  // b0 hi
      bf16x8 a01 = bc2(pf[sl][2], pf[sl][3]);  // b0 lo
      bf16x8 a10 = bc2(pf[sl][4], pf[sl][5]);  // b1 hi
      bf16x8 a11 = bc2(pf[sl][6], pf[sl][7]);  // b1 lo
      if (kt < 12) {
        #pragma unroll
        for (int q = 0; q < 8; ++q)
          pf[sl][q] = sld64(&ws->afr[l][pp][q >> 2][(q >> 1) & 1][wv][kt + 4][lane][q & 1]);
      }
      accg[0] = mfma16(a00, wgh[kt], accg[0]);
      accg[0] = mfma16(a00, wgl[kt], accg[0]);
      accg[0] = mfma16(a01, wgh[kt], accg[0]);
      acct[0] = mfma16(a00, wth[kt], acct[0]);
      acct[0] = mfma16(a00, wtl[kt], acct[0]);
      acct[0] = mfma16(a01, wth[kt], acct[0]);
      accg[1] = mfma16(a10, wgh[kt], accg[1]);
      accg[1] = mfma16(a10, wgl[kt], accg[1]);
      accg[1] = mfma16(a11, wgh[kt], accg[1]);
      acct[1] = mfma16(a10, wth[kt], acct[1]);
      acct[1] = mfma16(a10, wtl[kt], acct[1]);
      acct[1] = mfma16(a11, wth[kt], acct[1]);
    }
    const int t = rec >> 1;
    const bool pub = (rec & 1) != 0;
    #pragma unroll
    for (int b = 0; b < 2; ++b) {
      float css = 0.f;
      #pragma unroll
      for (int r = 0; r < 4; ++r) {
        float sig = 1.f / (1.f + expf(-accg[b][r]));
        float nv = ms[b][r] + sig * tanhf(acct[b][r]);
        ms[b][r] = nv;
        css += nv;
        unsigned hi = bf16r(nv);
        unsigned lo = bf16r(nv - __uint_as_float(hi << 16));
        sm.gx.xch[wv][b][4 * lq + r][c15] = hi | (lo << 16);
      }
      if (pub) {
        css += __shfl_xor(css, 16);
        css += __shfl_xor(css, 32);
        if (lane < 16) sm.gx.colp[wv][b][lane] = css;
      }
    }
    __syncthreads();
    // publish A-fragments for next rec (lane task: b = lane>>5, o2, row)
    {
      const int b = lane >> 5, o2 = (lane >> 4) & 1, row = lane & 15;
      unsigned x[8];
      #pragma unroll
      for (int j = 0; j < 8; ++j) x[j] = sm.gx.xch[wv][b][row][o2 * 8 + j];
      unsigned hw[4], lw[4];
      #pragma unroll
      for (int j = 0; j < 4; ++j) {
        hw[j] = (x[2 * j] & 0xffffu) | ((x[2 * j + 1] & 0xffffu) << 16);
        lw[j] = (x[2 * j] >> 16) | (x[2 * j + 1] & 0xffff0000u);
      }
      const int lt = lt_base + 16 * o2 + row;
      sst64(&ws->afr[l][np][b][0][wv][ktp][lt][0], hw[0] | ((unsigned long long)hw[1] << 32));
      sst64(&ws->afr[l][np][b][0][wv][ktp][lt][1], hw[2] | ((unsigned long long)hw[3] << 32));
      sst64(&ws->afr[l][np][b][1][wv][ktp][lt][0], lw[0] | ((unsigned long long)lw[1] << 32));
      sst64(&ws->afr[l][np][b][1][wv][ktp][lt][1], lw[2] | ((unsigned long long)lw[3] << 32));
    }
    if (pub && tid < 32) {
      int b = tid >> 4, c = tid & 15;
      float s = 0.f;
      #pragma unroll
      for (int w = 0; w < 8; ++w) s += sm.gx.colp[w][b][c];
      sstore(&ws->gcol[l][t][b][16 * ct + c], s);  // exclusive col owner
    }
    __builtin_amdgcn_s_waitcnt(0);
    __syncthreads();
    if (tid == 0) {
      __hip_atomic_fetch_add(&ws->grc[l], 1u, __ATOMIC_RELAXED, __HIP_MEMORY_SCOPE_AGENT);
      if (pub)
        __hip_atomic_fetch_add(&ws->gcol_cnt2[l][t], 1u, __ATOMIC_RELAXED, __HIP_MEMORY_SCOPE_AGENT);
    }
    if (rec + 1 < 2 * T) cwait(&ws->grc[l], (unsigned)(NGB * (rec + 1)));
  }
  #pragma unroll
  for (int b = 0; b < 2; ++b)
    #pragma unroll
    for (int r = 0; r < 4; ++r)
      fs[((((long)l * B + b) * H) + A + 16 * wv + 4 * lq + r) * H + 16 * ct + c15] = ms[b][r];
}

// ------------------------------------------------------- x layer-set (32 roles)
__device__ void x_set(int l, int role, WS* ws, SMem& sm,
                      const int* ids, const float* emb,
                      const float* nx_w, const float* nx_b,
                      const float* Wp, const float* bp,
                      const float* ns_w, const float* ns_b,
                      const float* W1, const float* b1,
                      const float* W2, const float* b2) {
  const int tid = threadIdx.x, wv = tid >> 6, lane = tid & 63;
  const long wb = (long)l * (A + H);
  const int v0r = role * 16, a0 = role * 64, c0 = role * 16;

  for (int i = tid; i < 16 * 256; i += NT) {
    int row = i >> 8, m = i & 255;
    const float* s = Wp + (wb + A + v0r + row) * H + 2 * m;
    sm.xp.wp[row][m] = bf16r(s[0]) | (bf16r(s[1]) << 16);
  }
  for (int i = tid; i < 64 * 256; i += NT) {
    int row = i >> 8, m = i & 255;
    const float* s = W1 + ((long)l * FF + a0 + row) * H + 2 * m;
    sm.xp.w1[row][m] = bf16r(s[0]) | (bf16r(s[1]) << 16);
  }
  for (int i = tid; i < 16 * 1024; i += NT) {
    int row = i >> 10, m = i & 1023;
    const float* s = W2 + ((long)l * H + c0 + row) * FF + 2 * m;
    sm.xp.w2[row][m] = bf16r(s[0]) | (bf16r(s[1]) << 16);
  }
  const float ic0 = ws->initcol[(l * B + 0) * H + tid];
  const float ic1 = ws->initcol[(l * B + 1) * H + tid];
  const float BU = ws->bus[l];
  const float bpA = bp[wb + A + tid];
  const float wU0 = ws->wU[l][tid];
  float as0 = 0.f, as1 = 0.f;
  __syncthreads();

  for (int t = 0; t < T; ++t) {
    // ---- P0 ----
    float xm0, xm1;
    if (l == 0) {
      xm0 = emb[(long)ids[t] * H + tid];
      xm1 = emb[(long)ids[T + t] * H + tid];
    } else {
      cwait(&ws->p3c[l - 1], (unsigned)(NXR * (t + 1)));
      xm0 = sload(&ws->xn[l - 1][t][0][tid]);
      xm1 = sload(&ws->xn[l - 1][t][1][tid]);
    }
    // ---- P1: LN1 + v-slice ----
    float2 ln = ln2reg(sm, xm0, xm1, nx_w + l * H, nx_b + l * H);
    float xr0[8], xr1[8];
    #pragma unroll
    for (int j = 0; j < 8; ++j) { xr0[j] = sm.xp.lnx[0][lane * 8 + j]; xr1[j] = sm.xp.lnx[1][lane * 8 + j]; }
    #pragma unroll
    for (int it = 0; it < 2; ++it) {
      int row = v0r + wv + it * 8;
      uint4 wq = *(const uint4*)&sm.xp.wp[row - v0r][lane * 4];
      float2 acc = wred2(d8(wq, xr0, xr1));
      if (lane == 0) {
        float bb = bp[wb + A + row];
        sstore(&ws->uv[t][l][0][A + row], acc.x + bb);
        sstore(&ws->uv[t][l][1][A + row], acc.y + bb);
      }
    }
    if (tid >= v0r && tid < v0r + 16) {
      sstore(&ws->lnxs[t][l][0][tid], ln.x);
      sstore(&ws->lnxs[t][l][1][tid], ln.y);
    }
    cdone(&ws->p1c[l]);
    float2 U1 = block_red2({wU0 * ln.x, wU0 * ln.y}, sm);
    cwait2(&ws->p1c[l], (unsigned)(NXR * (t + 1)),
           &ws->gcol_cnt2[l][t], (unsigned)NGB);
    // ---- P2: asum, xm, LN2, W1 ----
    float v0 = sload(&ws->uv[t][l][0][A + tid]);
    float v1 = sload(&ws->uv[t][l][1][A + tid]);
    float gc0 = sload(&ws->gcol[l][t][0][tid]);
    float gc1 = sload(&ws->gcol[l][t][1][tid]);
    as0 += (U1.x + BU) * v0;
    as1 += (U1.y + BU) * v1;
    float tb = (float)(t + 1) * BU * bpA;
    xm0 += (as0 + ic0 + tb + gc0) * (1.f / H);
    xm1 += (as1 + ic1 + tb + gc1) * (1.f / H);
    if (tid >= c0 && tid < c0 + 16) { sm.xp.xms[0][tid - c0] = xm0; sm.xp.xms[1][tid - c0] = xm1; }
    ln = ln2reg(sm, xm0, xm1, ns_w + l * H, ns_b + l * H);
    #pragma unroll
    for (int j = 0; j < 8; ++j) { xr0[j] = sm.xp.lnx[0][lane * 8 + j]; xr1[j] = sm.xp.lnx[1][lane * 8 + j]; }
    #pragma unroll
    for (int it = 0; it < 8; ++it) {
      int row = a0 + wv + it * 8;
      uint4 wq = *(const uint4*)&sm.xp.w1[row - a0][lane * 4];
      float2 acc = wred2(d8(wq, xr0, xr1));
      if (lane == 0) {
        float bb = b1[(long)l * FF + row];
        float z0 = acc.x + bb, z1 = acc.y + bb;
        sstore(&ws->hbuf[l][t & 1][0][row], 0.5f * z0 * (1.f + erff(z0 * 0.70710678118f)));
        sstore(&ws->hbuf[l][t & 1][1][row], 0.5f * z1 * (1.f + erff(z1 * 0.70710678118f)));
      }
    }
    cdone(&ws->p2c[l]);
    cwait(&ws->p2c[l], (unsigned)(NXR * (t + 1)));
    // ---- P3: gather h (bf16), W2, residual ----
    for (int i = tid; i < 2048; i += NT) {
      int b = i >> 10, m = i & 1023;
      float h0 = sload(&ws->hbuf[l][t & 1][b][2 * m]);
      float h1 = sload(&ws->hbuf[l][t & 1][b][2 * m + 1]);
      sm.xp.hb[b][m] = bf16r(h0) | (bf16r(h1) << 16);
    }
    __syncthreads();
    unsigned h0r[16], h1r[16];
    #pragma unroll
    for (int q = 0; q < 16; ++q) { h0r[q] = sm.xp.hb[0][lane + 64 * q]; h1r[q] = sm.xp.hb[1][lane + 64 * q]; }
    #pragma unroll
    for (int it = 0; it < 2; ++it) {
      int row = c0 + wv + it * 8;
      float2 acc{0.f, 0.f};
      #pragma unroll
      for (int q = 0; q < 16; ++q) {
        unsigned w = sm.xp.w2[row - c0][lane + 64 * q];
        float wl = __uint_as_float(w << 16), wh = __uint_as_float(w & 0xffff0000u);
        acc.x += wl * __uint_as_float(h0r[q] << 16) + wh * __uint_as_float(h0r[q] & 0xffff0000u);
        acc.y += wl * __uint_as_float(h1r[q] << 16) + wh * __uint_as_float(h1r[q] & 0xffff0000u);
      }
      acc = wred2(acc);
      if (lane == 0) {
        float bb = b2[(long)l * H + row];
        float o0 = sm.xp.xms[0][row - c0] + acc.x + bb;
        float o1 = sm.xp.xms[1][row - c0] + acc.y + bb;
        if (l == L - 1) {
          sstore(&ws->outs[t][0][row], o0);
          sstore(&ws->outs[t][1][row], o1);
        } else {
          sstore(&ws->xn[l][t][0][row], o0);
          sstore(&ws->xn[l][t][1][row], o1);
        }
      }
    }
    cdone(&ws->p3c[l]);
  }
}

// ------------------------------------------------------- prologue pack
__global__ __launch_bounds__(256) void pack_kernel(const float* __restrict__ Wg,
                                                   const float* __restrict__ Wt,
                                                   const float* __restrict__ states,
                                                   const float* __restrict__ bp,
                                                   const float* __restrict__ Wp,
                                                   WS* ws) {
  const int bid = blockIdx.x, tid = threadIdx.x;
  if (bid < 1024) {
    #pragma unroll
    for (int rep = 0; rep < 2; ++rep) {
      unsigned f = (unsigned)bid * 512u + (unsigned)rep * 256u + (unsigned)tid;
      int lane = f & 63, ct = (f >> 6) & 31, kt = (f >> 11) & 15;
      int split = (f >> 15) & 1, mat = (f >> 16) & 1, l = f >> 17;
      int o = ct * 16 + (lane & 15), kb = kt * 32 + ((lane >> 4) << 3);
      const float* src = (mat ? Wt : Wg) + ((long)l * H + o) * H + kb;
      unsigned v8[8];
      #pragma unroll
      for (int j = 0; j < 8; ++j) {
        float w = src[j];
        unsigned h = bf16r(w);
        if (split) h = bf16r(w - __uint_as_float(h << 16));
        v8[j] = h;
      }
      uint4 u;
      u.x = v8[0] | (v8[1] << 16); u.y = v8[2] | (v8[3] << 16);
      u.z = v8[4] | (v8[5] << 16); u.w = v8[6] | (v8[7] << 16);
      ws->bpk[l][mat][split][kt][ct][lane] = u;
    }
  } else if (bid < 1032) {
    int lb = bid - 1024, l = lb >> 1, b = lb & 1;
    #pragma unroll
    for (int half = 0; half < 2; ++half) {
      int col = tid + half * 256;
      float acc = 0.f;
      for (int i = 0; i < A; ++i)
        acc += states[(((long)l * B + b) * H + i) * H + col];
      ws->initcol[(l * B + b) * H + col] = acc;
    }
  } else if (bid == 1032) {
    __shared__ float tmp[256];
    int l = tid >> 6, i = tid & 63;
    float p = 0.f;
    for (int j = 0; j < 6; ++j) p += bp[(long)l * (A + H) + j * 64 + i];
    tmp[tid] = p;
    __syncthreads();
    if (tid < 4) {
      float s = 0.f;
      for (int q = 0; q < 64; ++q) s += tmp[tid * 64 + q];
      ws->bus[tid] = s;
    }
  } else if (bid < 1037) {
    int l = bid - 1033;
    #pragma unroll
    for (int half = 0; half < 2; ++half) {
      int k = tid + half * 256;
      float acc = 0.f;
      for (int i = 0; i < A; ++i)
        acc += Wp[((long)l * (A + H) + i) * H + k];
      ws->wU[l][k] = acc;
    }
  } else {
    // seed afr[l][pp=0][b] from initial states
    int q = bid - 1037, l = q >> 1, b = q & 1;
    for (int i = tid; i < 32768; i += 256) {
      int half = i & 1, lane = (i >> 1) & 63, kt = (i >> 7) & 15;
      int rt = (i >> 11) & 7, sp = (i >> 14) & 1;
      int g = 16 * rt + (lane & 15);
      int kb = 32 * kt + 8 * (lane >> 4) + 4 * half;
      const float* src = states + ((((long)l * B + b) * H) + A + g) * H + kb;
      unsigned v4[4];
      #pragma unroll
      for (int j = 0; j < 4; ++j) {
        float w = src[j];
        unsigned h = bf16r(w);
        if (sp) h = bf16r(w - __uint_as_float(h << 16));
        v4[j] = h;
      }
      unsigned w0 = v4[0] | (v4[1] << 16), w1 = v4[2] | (v4[3] << 16);
      ws->afr[l][0][b][sp][rt][kt][lane][half] = w0 | ((unsigned long long)w1 << 32);
    }
  }
}

// ------------------------------------------------------- main kernel
__global__ __launch_bounds__(NT, 1) void vega_kernel(
    const int* __restrict__ ids, const float* __restrict__ states,
    const float* __restrict__ emb,
    const float* __restrict__ nx_w, const float* __restrict__ nx_b,
    const float* __restrict__ Wp, const float* __restrict__ bp,
    const float* __restrict__ ns_w, const float* __restrict__ ns_b,
    const float* __restrict__ W1, const float* __restrict__ b1,
    const float* __restrict__ W2, const float* __restrict__ b2,
    const float* __restrict__ on_w, const float* __restrict__ on_b,
    const float* __restrict__ head_W, const float* __restrict__ head_b,
    float* __restrict__ out, WS* ws) {
  __shared__ SMem sm;
  const int bid = blockIdx.x, tid = threadIdx.x;
  float* fs = out + LOGITS;

  if (bid < 128) {
    ghost_regs(bid >> 5, bid & 31, ws, sm, states, fs);
  } else {
    int xb = bid - 128;
    x_set(xb >> 5, xb & 31, ws, sm, ids, emb, nx_w, nx_b, Wp, bp,
          ns_w, ns_b, W1, b1, W2, b2);
  }

  gbar(ws);

  // -------- E1: fstates reconstruction (u from lnx) + final LN of outs --------
  if (bid < 192) {
    int lb = bid / 24, sub = bid % 24;
    int l = lb >> 1, b = lb & 1, r0 = sub * 16;
    const long wb = (long)l * (A + H);
    const int row = tid >> 5, kc = tid & 31;
    float wreg[16];
    {
      const float* wr = Wp + (wb + r0 + row) * H + kc * 16;
      #pragma unroll
      for (int jj = 0; jj < 16; ++jj) wreg[jj] = wr[jj];
    }
    const float bprow = bp[wb + r0 + row];
    float pre = sload(&ws->lnxs[0][l][b][tid]);
    for (int t2 = 0; t2 < T; ++t2) {
      sm.e1.lnx[tid] = pre;
      __syncthreads();
      if (t2 + 1 < T) pre = sload(&ws->lnxs[t2 + 1][l][b][tid]);
      float part = 0.f;
      #pragma unroll
      for (int jj = 0; jj < 16; ++jj) part += wreg[jj] * sm.e1.lnx[kc * 16 + jj];
      #pragma unroll
      for (int off = 1; off < 32; off <<= 1) part += __shfl_xor(part, off);
      if (kc == 0) sm.e1.u16[t2][row] = part + bprow;
      __syncthreads();
    }
    float bv = bp[wb + A + tid];
    float acc[16];
    #pragma unroll
    for (int q = 0; q < 16; ++q) acc[q] = 32.f * bp[wb + r0 + q] * bv;
    for (int t2 = 0; t2 < T; ++t2) {
      float vv = sload(&ws->uv[t2][l][b][A + tid]);
      #pragma unroll
      for (int q = 0; q < 16; ++q) acc[q] = fmaf(sm.e1.u16[t2][q], vv, acc[q]);
    }
    #pragma unroll
    for (int q = 0; q < 16; ++q)
      fs[(((long)l * B + b) * H + (r0 + q)) * H + tid] =
          states[(((long)l * B + b) * H + (r0 + q)) * H + tid] + acc[q];
  }
  if (bid < T * B) {
    int row = bid, t = row >> 1, b = row & 1;
    ln512(sm, ws->outs[t][b], ws->lnouts[row], on_w, on_b);
  }

  gbar(ws);

  // -------- E2: head GEMM (64 rows x 125 vocab per block, K=512) --------
  {
    const int wv = tid >> 6, lane = tid & 63;
    const long vbase = (long)bid * 125;
    float acc[16];
    #pragma unroll
    for (int q = 0; q < 16; ++q) acc[q] = 0.f;
    for (int cc = 0; cc < 8; ++cc) {
      float4 xr[16];
      #pragma unroll
      for (int q = 0; q < 16; ++q)
        xr[q] = *(const float4*)&ws->lnouts[lane][cc * 64 + q * 4];
      #pragma unroll
      for (int vi = 0; vi < 16; ++vi) {
        int vloc = vi * 8 + wv;
        if (vloc < 125) {
          const float4* wp_ = (const float4*)(head_W + (vbase + vloc) * H + cc * 64);
          float s = 0.f;
          #pragma unroll
          for (int q = 0; q < 16; ++q) s += dot4(xr[q], wp_[q]);
          acc[vi] += s;
        }
      }
    }
    #pragma unroll
    for (int vi = 0; vi < 16; ++vi) {
      int vloc = vi * 8 + wv;
      if (vloc < 125) sm.hd.tile[vloc][lane] = acc[vi] + head_b[vbase + vloc];
    }
    __syncthreads();
    for (int idx = tid; idx < 64 * 125; idx += NT) {
      int row = idx / 125, vl = idx % 125;
      int t = row >> 1, b = row & 1;
      out[((long)(b * T + t)) * V + vbase + vl] = sm.hd.tile[vl][row];
    }
  }
}

}  // namespace

extern "C" void kernel_launch(void* const* d_in, const int* in_sizes, int n_in,
                              void* d_out, int out_size, void* d_ws, size_t ws_size,
                              hipStream_t stream) {
  (void)in_sizes; (void)n_in; (void)out_size; (void)ws_size;
  const int*   ids    = (const int*)d_in[0];
  const float* states = (const float*)d_in[1];
  const float* emb    = (const float*)d_in[2];
  const float* nx_w   = (const float*)d_in[3];
  const float* nx_b   = (const float*)d_in[4];
  const float* Wp     = (const float*)d_in[5];
  const float* bp     = (const float*)d_in[6];
  const float* Wg     = (const float*)d_in[7];
  const float* Wt     = (const float*)d_in[8];
  const float* ns_w   = (const float*)d_in[9];
  const float* ns_b   = (const float*)d_in[10];
  const float* W1     = (const float*)d_in[11];
  const float* b1     = (const float*)d_in[12];
  const float* W2     = (const float*)d_in[13];
  const float* b2     = (const float*)d_in[14];
  const float* on_w   = (const float*)d_in[15];
  const float* on_b   = (const float*)d_in[16];
  const float* head_W = (const float*)d_in[17];
  const float* head_b = (const float*)d_in[18];
  float* out = (float*)d_out;
  WS* ws = (WS*)d_ws;

  (void)hipMemsetAsync(d_ws, 0, offsetof(WS, uv), stream);
  pack_kernel<<<dim3(1045), dim3(256), 0, stream>>>(Wg, Wt, states, bp, Wp, ws);
  vega_kernel<<<dim3(GRID), dim3(NT), 0, stream>>>(
      ids, states, emb, nx_w, nx_b, Wp, bp, ns_w, ns_b,
      W1, b1, W2, b2, on_w, on_b, head_W, head_b, out, ws);
}

// Round 11
// 1640.018 us; speedup vs baseline: 2.8098x; 1.7833x over previous
//
#include <hip/hip_runtime.h>
#include <hip/hip_bf16.h>
#include <math.h>
#include <stddef.h>

namespace {

constexpr int V = 32000, H = 512, L = 4, A = 384, B = 2, T = 32, FF = 2048;
constexpr long LOGITS = (long)B * T * V;   // 2,048,000
constexpr int GRID = 256, NT = 512;
constexpr int NXR = 32;                    // x roles per layer
constexpr int NGB = 32;                    // ghost blocks per layer (col-sliced)
constexpr float EPS = 1e-5f;

typedef short bf16x8 __attribute__((ext_vector_type(8)));
typedef float f32x4 __attribute__((ext_vector_type(4)));
typedef unsigned long long ull;
typedef unsigned long long ull2 __attribute__((ext_vector_type(2)));

struct WS {
  // ---- zeroed region ----
  unsigned gbar_cnt, gbar_gen;
  unsigned pad0[62];
  unsigned p1c[L], p2c[L], p3c[L], grc[L];
  unsigned pad1[48];
  unsigned gcol_cnt2[L][T];
  unsigned gxcnt[L];
  unsigned gxcd[L][NGB];
  unsigned pad2[64];
  float gcol[L][T][B][H];
  // ---- not zeroed (fully written before read every launch) ----
  float uv[T][L][B][A + H];
  float lnxs[T][L][B][H];
  float outs[T][B][H];
  float lnouts[T * B][H];
  float xn[3][T][B][H];
  float hbuf[L][2][B][FF];
  float initcol[L * B * H];
  float bus[4];
  float wU[L][H];
  uint4 bpk[L][2][2][16][32][64];      // ghost W frag-packed (hi/lo split)
  ull afr[L][2][2][2][8][16][64][2];   // A-frag exchange [l][pp][b][split][rt][kt][lane][half]
};

union __align__(16) SMem {
  struct { unsigned xch[8][2][16][16]; float colp[8][2][16]; } gx;  // 17 KB (ghost)
  struct {
    unsigned wp[16][256];   // Wp v-rows, bf16 pair (2m,2m+1)
    unsigned w1[64][256];
    unsigned w2[16][1024];  // pair (2m,2m+1)
    float lnx[2][512];
    unsigned hb[2][1024];   // h as bf16 pairs
    float xms[2][16];
    float2 red[8];
  } xp;                     // ~156 KB
  struct { float u16[T][16]; float lnx[H]; } e1;
  struct { float tile[125][64]; } hd;
};

__device__ __forceinline__ float dot4(const float4& a, const float4& b) {
  return a.x * b.x + a.y * b.y + a.z * b.z + a.w * b.w;
}
__device__ __forceinline__ unsigned bf16r(float f) {
  unsigned u = __float_as_uint(f);
  return (u + 0x7fffu + ((u >> 16) & 1u)) >> 16;
}
// system-scope relaxed: uncached, coherence-point reads/writes
__device__ __forceinline__ float sload(const float* p) {
  return __hip_atomic_load(p, __ATOMIC_RELAXED, __HIP_MEMORY_SCOPE_SYSTEM);
}
__device__ __forceinline__ void sstore(float* p, float v) {
  __hip_atomic_store(p, v, __ATOMIC_RELAXED, __HIP_MEMORY_SCOPE_SYSTEM);
}
__device__ __forceinline__ ull sld64(const ull* p) {
  return __hip_atomic_load(p, __ATOMIC_RELAXED, __HIP_MEMORY_SCOPE_SYSTEM);
}
__device__ __forceinline__ void sst64(ull* p, ull v) {
  __hip_atomic_store(p, v, __ATOMIC_RELAXED, __HIP_MEMORY_SCOPE_SYSTEM);
}
// agent(device)-scope relaxed: bypasses L1, L2-cacheable
__device__ __forceinline__ ull ald64(const ull* p) {
  return __hip_atomic_load(p, __ATOMIC_RELAXED, __HIP_MEMORY_SCOPE_AGENT);
}
__device__ __forceinline__ void ast64(ull* p, ull v) {
  __hip_atomic_store(p, v, __ATOMIC_RELAXED, __HIP_MEMORY_SCOPE_AGENT);
}
__device__ __forceinline__ unsigned sload_u(const unsigned* p) {
  return __hip_atomic_load(p, __ATOMIC_RELAXED, __HIP_MEMORY_SCOPE_SYSTEM);
}
__device__ __forceinline__ f32x4 mfma16(bf16x8 a, bf16x8 b, f32x4 c) {
  return __builtin_amdgcn_mfma_f32_16x16x32_bf16(a, b, c, 0, 0, 0);
}
__device__ __forceinline__ bf16x8 bc2(ull a, ull b) {
  ull2 t; t.x = a; t.y = b;
  return __builtin_bit_cast(bf16x8, t);
}
__device__ __forceinline__ bf16x8 bcu4(uint4 u) {
  return __builtin_bit_cast(bf16x8, u);
}

// FAST = intra-XCD L2 fabric (agent-scope atomics: L1-bypass, L2-served);
// !FAST = system scope (coherence point), r9-proven.
template <bool FAST>
__device__ __forceinline__ bf16x8 ld_afr(const ull* p) {
  if (FAST) return bc2(ald64(p), ald64(p + 1));
  else      return bc2(sld64(p), sld64(p + 1));
}
template <bool FAST>
__device__ __forceinline__ void st_afr(ull* p, ull lo, ull hi) {
  if (FAST) { ast64(p, lo); ast64(p + 1, hi); }
  else      { sst64(p, lo); sst64(p + 1, hi); }
}

__device__ void wait_u32(unsigned* p, unsigned target) {
  int spin = 0;
  while (__hip_atomic_load(p, __ATOMIC_RELAXED, __HIP_MEMORY_SCOPE_AGENT) < target) {
    __builtin_amdgcn_s_sleep(8);
    if ((++spin & 63) == 0)
      (void)__hip_atomic_load(p, __ATOMIC_ACQUIRE, __HIP_MEMORY_SCOPE_AGENT);
  }
}

__device__ void gbar(WS* ws) {
  __syncthreads();
  if (threadIdx.x == 0) {
    __threadfence();
    unsigned g = __hip_atomic_load(&ws->gbar_gen, __ATOMIC_RELAXED, __HIP_MEMORY_SCOPE_AGENT);
    unsigned a = __hip_atomic_fetch_add(&ws->gbar_cnt, 1u, __ATOMIC_ACQ_REL, __HIP_MEMORY_SCOPE_AGENT);
    if (a == (unsigned)(GRID - 1)) {
      __hip_atomic_store(&ws->gbar_cnt, 0u, __ATOMIC_RELAXED, __HIP_MEMORY_SCOPE_AGENT);
      __hip_atomic_fetch_add(&ws->gbar_gen, 1u, __ATOMIC_RELEASE, __HIP_MEMORY_SCOPE_AGENT);
    } else {
      wait_u32(&ws->gbar_gen, g + 1);
    }
    __threadfence();
  }
  __syncthreads();
}

__device__ void cdone(unsigned* p) {
  __builtin_amdgcn_s_waitcnt(0);
  __syncthreads();
  if (threadIdx.x == 0)
    __hip_atomic_fetch_add(p, 1u, __ATOMIC_RELAXED, __HIP_MEMORY_SCOPE_AGENT);
}
__device__ void cwait(unsigned* p, unsigned tgt) {
  if (threadIdx.x == 0) {
    int spin = 0;
    while (sload_u(p) < tgt) {
      __builtin_amdgcn_s_sleep(2);
      if ((++spin & 1023) == 0)
        (void)__hip_atomic_load(p, __ATOMIC_ACQUIRE, __HIP_MEMORY_SCOPE_AGENT);
    }
  }
  __syncthreads();
}
__device__ void cwait2(unsigned* pa, unsigned ta, unsigned* pb, unsigned tbv) {
  if (threadIdx.x < 64) {
    unsigned* p = pa;
    unsigned tg = ta;
    if (threadIdx.x == 1) { p = pb; tg = tbv; }
    const bool act = threadIdx.x < 2;
    int spin = 0;
    for (;;) {
      bool ok = !act || sload_u(p) >= tg;
      if (__all(ok)) break;
      __builtin_amdgcn_s_sleep(2);
      if ((++spin & 1023) == 0 && act)
        (void)__hip_atomic_load(p, __ATOMIC_ACQUIRE, __HIP_MEMORY_SCOPE_AGENT);
    }
  }
  __syncthreads();
}

__device__ float2 wred2(float2 v) {
  #pragma unroll
  for (int off = 1; off < 64; off <<= 1) {
    v.x += __shfl_xor(v.x, off);
    v.y += __shfl_xor(v.y, off);
  }
  return v;
}

__device__ float2 block_red2(float2 v, SMem& sm) {
  v = wred2(v);
  int w = threadIdx.x >> 6;
  __syncthreads();
  if ((threadIdx.x & 63) == 0) sm.xp.red[w] = v;
  __syncthreads();
  float2 s{0.f, 0.f};
  #pragma unroll
  for (int q = 0; q < 8; ++q) { s.x += sm.xp.red[q].x; s.y += sm.xp.red[q].y; }
  return s;
}

__device__ void ln512(SMem& sm, const float* in, float* outp,
                      const float* w, const float* b) {
  int tid = threadIdx.x;
  float xv = in[tid];
  float m = block_red2({xv, 0.f}, sm).x * (1.f / H);
  float d = xv - m;
  float var = block_red2({d * d, 0.f}, sm).x * (1.f / H);
  float inv = rsqrtf(var + EPS);
  outp[tid] = d * inv * w[tid] + b[tid];
  __syncthreads();
}

__device__ float2 ln2reg(SMem& sm, float x0, float x1, const float* w, const float* b) {
  int tid = threadIdx.x;
  float2 mm = block_red2({x0, x1}, sm);
  float d0 = x0 - mm.x * (1.f / H), d1 = x1 - mm.y * (1.f / H);
  float2 vv = block_red2({d0 * d0, d1 * d1}, sm);
  float i0 = rsqrtf(vv.x * (1.f / H) + EPS), i1 = rsqrtf(vv.y * (1.f / H) + EPS);
  float wv_ = w[tid], bv = b[tid];
  float l0 = d0 * i0 * wv_ + bv, l1 = d1 * i1 * wv_ + bv;
  sm.xp.lnx[0][tid] = l0;
  sm.xp.lnx[1][tid] = l1;
  __syncthreads();
  return {l0, l1};
}

__device__ __forceinline__ float2 d8(uint4 wq, const float* xr0, const float* xr1) {
  float2 a{0.f, 0.f};
  unsigned u[4] = {wq.x, wq.y, wq.z, wq.w};
  #pragma unroll
  for (int j = 0; j < 4; ++j) {
    float wl = __uint_as_float(u[j] << 16);
    float wh = __uint_as_float(u[j] & 0xffff0000u);
    a.x = fmaf(wl, xr0[2 * j], fmaf(wh, xr0[2 * j + 1], a.x));
    a.y = fmaf(wl, xr1[2 * j], fmaf(wh, xr1[2 * j + 1], a.y));
  }
  return a;
}

// ------------------------------------------------------- ghost
template <bool FAST>
__device__ void ghost_regs(int l, int ct, WS* ws, SMem& sm,
                           const float* __restrict__ states, float* __restrict__ fs) {
  const int tid = threadIdx.x, wv = tid >> 6, lane = tid & 63;
  const int c15 = lane & 15, lq = lane >> 4;
  // master state in regs: lane owns rows 16*wv+4*lq+r, col 16*ct+c15, both b
  float ms[2][4];
  #pragma unroll
  for (int b = 0; b < 2; ++b)
    #pragma unroll
    for (int r = 0; r < 4; ++r)
      ms[b][r] = states[((((long)l * B + b) * H) + A + 16 * wv + 4 * lq + r) * H + 16 * ct + c15];

  const int ktp = ct >> 1;
  const int lt_base = 32 * (ct & 1);

  #pragma unroll 1
  for (int rec = 0; rec < 2 * T; ++rec) {
    const int pp = rec & 1, np = pp ^ 1;
    asm volatile("" ::: "memory");
    f32x4 accg[2], acct[2];
    #pragma unroll
    for (int b = 0; b < 2; ++b) { accg[b] = {0.f,0.f,0.f,0.f}; acct[b] = {0.f,0.f,0.f,0.f}; }
    #pragma unroll 4
    for (int kt = 0; kt < 16; ++kt) {
      bf16x8 a00 = ld_afr<FAST>(&ws->afr[l][pp][0][0][wv][kt][lane][0]);
      bf16x8 a01 = ld_afr<FAST>(&ws->afr[l][pp][0][1][wv][kt][lane][0]);
      bf16x8 a10 = ld_afr<FAST>(&ws->afr[l][pp][1][0][wv][kt][lane][0]);
      bf16x8 a11 = ld_afr<FAST>(&ws->afr[l][pp][1][1][wv][kt][lane][0]);
      bf16x8 bgh = bcu4(ws->bpk[l][0][0][kt][ct][lane]);
      bf16x8 bgl = bcu4(ws->bpk[l][0][1][kt][ct][lane]);
      bf16x8 bth = bcu4(ws->bpk[l][1][0][kt][ct][lane]);
      bf16x8 btl = bcu4(ws->bpk[l][1][1][kt][ct][lane]);
      accg[0] = mfma16(a00, bgh, accg[0]);
      accg[0] = mfma16(a00, bgl, accg[0]);
      accg[0] = mfma16(a01, bgh, accg[0]);
      acct[0] = mfma16(a00, bth, acct[0]);
      acct[0] = mfma16(a00, btl, acct[0]);
      acct[0] = mfma16(a01, bth, acct[0]);
      accg[1] = mfma16(a10, bgh, accg[1]);
      accg[1] = mfma16(a10, bgl, accg[1]);
      accg[1] = mfma16(a11, bgh, accg[1]);
      acct[1] = mfma16(a10, bth, acct[1]);
      acct[1] = mfma16(a10, btl, acct[1]);
      acct[1] = mfma16(a11, bth, acct[1]);
    }
    const int t = rec >> 1;
    const bool pub = (rec & 1) != 0;
    #pragma unroll
    for (int b = 0; b < 2; ++b) {
      float css = 0.f;
      #pragma unroll
      for (int r = 0; r < 4; ++r) {
        float sig = 1.f / (1.f + expf(-accg[b][r]));
        float nv = ms[b][r] + sig * tanhf(acct[b][r]);
        ms[b][r] = nv;
        css += nv;
        unsigned hi = bf16r(nv);
        unsigned lo = bf16r(nv - __uint_as_float(hi << 16));
        sm.gx.xch[wv][b][4 * lq + r][c15] = hi | (lo << 16);
      }
      if (pub) {
        css += __shfl_xor(css, 16);
        css += __shfl_xor(css, 32);
        if (lane < 16) sm.gx.colp[wv][b][lane] = css;
      }
    }
    __syncthreads();
    // publish A-fragments for next rec (lane task: b = lane>>5, o2, row)
    {
      const int b = lane >> 5, o2 = (lane >> 4) & 1, row = lane & 15;
      unsigned x[8];
      #pragma unroll
      for (int j = 0; j < 8; ++j) x[j] = sm.gx.xch[wv][b][row][o2 * 8 + j];
      unsigned hw[4], lw[4];
      #pragma unroll
      for (int j = 0; j < 4; ++j) {
        hw[j] = (x[2 * j] & 0xffffu) | ((x[2 * j + 1] & 0xffffu) << 16);
        lw[j] = (x[2 * j] >> 16) | (x[2 * j + 1] & 0xffff0000u);
      }
      const int lt = lt_base + 16 * o2 + row;
      st_afr<FAST>(&ws->afr[l][np][b][0][wv][ktp][lt][0],
                   hw[0] | ((ull)hw[1] << 32), hw[2] | ((ull)hw[3] << 32));
      st_afr<FAST>(&ws->afr[l][np][b][1][wv][ktp][lt][0],
                   lw[0] | ((ull)lw[1] << 32), lw[2] | ((ull)lw[3] << 32));
    }
    if (pub && tid < 32) {
      int b = tid >> 4, c = tid & 15;
      float s = 0.f;
      #pragma unroll
      for (int w = 0; w < 8; ++w) s += sm.gx.colp[w][b][c];
      sstore(&ws->gcol[l][t][b][16 * ct + c], s);  // exclusive col owner
    }
    asm volatile("" ::: "memory");
    __builtin_amdgcn_s_waitcnt(0);
    __syncthreads();
    if (tid == 0) {
      __hip_atomic_fetch_add(&ws->grc[l], 1u, __ATOMIC_RELAXED, __HIP_MEMORY_SCOPE_AGENT);
      if (pub)
        __hip_atomic_fetch_add(&ws->gcol_cnt2[l][t], 1u, __ATOMIC_RELAXED, __HIP_MEMORY_SCOPE_AGENT);
    }
    if (rec + 1 < 2 * T) cwait(&ws->grc[l], (unsigned)(NGB * (rec + 1)));
  }
  #pragma unroll
  for (int b = 0; b < 2; ++b)
    #pragma unroll
    for (int r = 0; r < 4; ++r)
      fs[((((long)l * B + b) * H) + A + 16 * wv + 4 * lq + r) * H + 16 * ct + c15] = ms[b][r];
}

// ------------------------------------------------------- x layer-set (32 roles)
__device__ void x_set(int l, int role, WS* ws, SMem& sm,
                      const int* ids, const float* emb,
                      const float* nx_w, const float* nx_b,
                      const float* Wp, const float* bp,
                      const float* ns_w, const float* ns_b,
                      const float* W1, const float* b1,
                      const float* W2, const float* b2) {
  const int tid = threadIdx.x, wv = tid >> 6, lane = tid & 63;
  const long wb = (long)l * (A + H);
  const int v0r = role * 16, a0 = role * 64, c0 = role * 16;

  for (int i = tid; i < 16 * 256; i += NT) {
    int row = i >> 8, m = i & 255;
    const float* s = Wp + (wb + A + v0r + row) * H + 2 * m;
    sm.xp.wp[row][m] = bf16r(s[0]) | (bf16r(s[1]) << 16);
  }
  for (int i = tid; i < 64 * 256; i += NT) {
    int row = i >> 8, m = i & 255;
    const float* s = W1 + ((long)l * FF + a0 + row) * H + 2 * m;
    sm.xp.w1[row][m] = bf16r(s[0]) | (bf16r(s[1]) << 16);
  }
  for (int i = tid; i < 16 * 1024; i += NT) {
    int row = i >> 10, m = i & 1023;
    const float* s = W2 + ((long)l * H + c0 + row) * FF + 2 * m;
    sm.xp.w2[row][m] = bf16r(s[0]) | (bf16r(s[1]) << 16);
  }
  const float ic0 = ws->initcol[(l * B + 0) * H + tid];
  const float ic1 = ws->initcol[(l * B + 1) * H + tid];
  const float BU = ws->bus[l];
  const float bpA = bp[wb + A + tid];
  const float wU0 = ws->wU[l][tid];
  float as0 = 0.f, as1 = 0.f;
  __syncthreads();

  for (int t = 0; t < T; ++t) {
    // ---- P0 ----
    float xm0, xm1;
    if (l == 0) {
      xm0 = emb[(long)ids[t] * H + tid];
      xm1 = emb[(long)ids[T + t] * H + tid];
    } else {
      cwait(&ws->p3c[l - 1], (unsigned)(NXR * (t + 1)));
      xm0 = sload(&ws->xn[l - 1][t][0][tid]);
      xm1 = sload(&ws->xn[l - 1][t][1][tid]);
    }
    // ---- P1: LN1 + v-slice ----
    float2 ln = ln2reg(sm, xm0, xm1, nx_w + l * H, nx_b + l * H);
    float xr0[8], xr1[8];
    #pragma unroll
    for (int j = 0; j < 8; ++j) { xr0[j] = sm.xp.lnx[0][lane * 8 + j]; xr1[j] = sm.xp.lnx[1][lane * 8 + j]; }
    #pragma unroll
    for (int it = 0; it < 2; ++it) {
      int row = v0r + wv + it * 8;
      uint4 wq = *(const uint4*)&sm.xp.wp[row - v0r][lane * 4];
      float2 acc = wred2(d8(wq, xr0, xr1));
      if (lane == 0) {
        float bb = bp[wb + A + row];
        sstore(&ws->uv[t][l][0][A + row], acc.x + bb);
        sstore(&ws->uv[t][l][1][A + row], acc.y + bb);
      }
    }
    if (tid >= v0r && tid < v0r + 16) {
      sstore(&ws->lnxs[t][l][0][tid], ln.x);
      sstore(&ws->lnxs[t][l][1][tid], ln.y);
    }
    cdone(&ws->p1c[l]);
    float2 U1 = block_red2({wU0 * ln.x, wU0 * ln.y}, sm);
    cwait2(&ws->p1c[l], (unsigned)(NXR * (t + 1)),
           &ws->gcol_cnt2[l][t], (unsigned)NGB);
    // ---- P2: asum, xm, LN2, W1 ----
    float v0 = sload(&ws->uv[t][l][0][A + tid]);
    float v1 = sload(&ws->uv[t][l][1][A + tid]);
    float gc0 = sload(&ws->gcol[l][t][0][tid]);
    float gc1 = sload(&ws->gcol[l][t][1][tid]);
    as0 += (U1.x + BU) * v0;
    as1 += (U1.y + BU) * v1;
    float tb = (float)(t + 1) * BU * bpA;
    xm0 += (as0 + ic0 + tb + gc0) * (1.f / H);
    xm1 += (as1 + ic1 + tb + gc1) * (1.f / H);
    if (tid >= c0 && tid < c0 + 16) { sm.xp.xms[0][tid - c0] = xm0; sm.xp.xms[1][tid - c0] = xm1; }
    ln = ln2reg(sm, xm0, xm1, ns_w + l * H, ns_b + l * H);
    #pragma unroll
    for (int j = 0; j < 8; ++j) { xr0[j] = sm.xp.lnx[0][lane * 8 + j]; xr1[j] = sm.xp.lnx[1][lane * 8 + j]; }
    #pragma unroll
    for (int it = 0; it < 8; ++it) {
      int row = a0 + wv + it * 8;
      uint4 wq = *(const uint4*)&sm.xp.w1[row - a0][lane * 4];
      float2 acc = wred2(d8(wq, xr0, xr1));
      if (lane == 0) {
        float bb = b1[(long)l * FF + row];
        float z0 = acc.x + bb, z1 = acc.y + bb;
        sstore(&ws->hbuf[l][t & 1][0][row], 0.5f * z0 * (1.f + erff(z0 * 0.70710678118f)));
        sstore(&ws->hbuf[l][t & 1][1][row], 0.5f * z1 * (1.f + erff(z1 * 0.70710678118f)));
      }
    }
    cdone(&ws->p2c[l]);
    cwait(&ws->p2c[l], (unsigned)(NXR * (t + 1)));
    // ---- P3: gather h (bf16), W2, residual ----
    for (int i = tid; i < 2048; i += NT) {
      int b = i >> 10, m = i & 1023;
      float h0 = sload(&ws->hbuf[l][t & 1][b][2 * m]);
      float h1 = sload(&ws->hbuf[l][t & 1][b][2 * m + 1]);
      sm.xp.hb[b][m] = bf16r(h0) | (bf16r(h1) << 16);
    }
    __syncthreads();
    unsigned h0r[16], h1r[16];
    #pragma unroll
    for (int q = 0; q < 16; ++q) { h0r[q] = sm.xp.hb[0][lane + 64 * q]; h1r[q] = sm.xp.hb[1][lane + 64 * q]; }
    #pragma unroll
    for (int it = 0; it < 2; ++it) {
      int row = c0 + wv + it * 8;
      float2 acc{0.f, 0.f};
      #pragma unroll
      for (int q = 0; q < 16; ++q) {
        unsigned w = sm.xp.w2[row - c0][lane + 64 * q];
        float wl = __uint_as_float(w << 16), wh = __uint_as_float(w & 0xffff0000u);
        acc.x += wl * __uint_as_float(h0r[q] << 16) + wh * __uint_as_float(h0r[q] & 0xffff0000u);
        acc.y += wl * __uint_as_float(h1r[q] << 16) + wh * __uint_as_float(h1r[q] & 0xffff0000u);
      }
      acc = wred2(acc);
      if (lane == 0) {
        float bb = b2[(long)l * H + row];
        float o0 = sm.xp.xms[0][row - c0] + acc.x + bb;
        float o1 = sm.xp.xms[1][row - c0] + acc.y + bb;
        if (l == L - 1) {
          sstore(&ws->outs[t][0][row], o0);
          sstore(&ws->outs[t][1][row], o1);
        } else {
          sstore(&ws->xn[l][t][0][row], o0);
          sstore(&ws->xn[l][t][1][row], o1);
        }
      }
    }
    cdone(&ws->p3c[l]);
  }
}

// ------------------------------------------------------- prologue pack
__global__ __launch_bounds__(256) void pack_kernel(const float* __restrict__ Wg,
                                                   const float* __restrict__ Wt,
                                                   const float* __restrict__ states,
                                                   const float* __restrict__ bp,
                                                   const float* __restrict__ Wp,
                                                   WS* ws) {
  const int bid = blockIdx.x, tid = threadIdx.x;
  if (bid < 1024) {
    #pragma unroll
    for (int rep = 0; rep < 2; ++rep) {
      unsigned f = (unsigned)bid * 512u + (unsigned)rep * 256u + (unsigned)tid;
      int lane = f & 63, ct = (f >> 6) & 31, kt = (f >> 11) & 15;
      int split = (f >> 15) & 1, mat = (f >> 16) & 1, l = f >> 17;
      int o = ct * 16 + (lane & 15), kb = kt * 32 + ((lane >> 4) << 3);
      const float* src = (mat ? Wt : Wg) + ((long)l * H + o) * H + kb;
      unsigned v8[8];
      #pragma unroll
      for (int j = 0; j < 8; ++j) {
        float w = src[j];
        unsigned h = bf16r(w);
        if (split) h = bf16r(w - __uint_as_float(h << 16));
        v8[j] = h;
      }
      uint4 u;
      u.x = v8[0] | (v8[1] << 16); u.y = v8[2] | (v8[3] << 16);
      u.z = v8[4] | (v8[5] << 16); u.w = v8[6] | (v8[7] << 16);
      ws->bpk[l][mat][split][kt][ct][lane] = u;
    }
  } else if (bid < 1032) {
    int lb = bid - 1024, l = lb >> 1, b = lb & 1;
    #pragma unroll
    for (int half = 0; half < 2; ++half) {
      int col = tid + half * 256;
      float acc = 0.f;
      for (int i = 0; i < A; ++i)
        acc += states[(((long)l * B + b) * H + i) * H + col];
      ws->initcol[(l * B + b) * H + col] = acc;
    }
  } else if (bid == 1032) {
    __shared__ float tmp[256];
    int l = tid >> 6, i = tid & 63;
    float p = 0.f;
    for (int j = 0; j < 6; ++j) p += bp[(long)l * (A + H) + j * 64 + i];
    tmp[tid] = p;
    __syncthreads();
    if (tid < 4) {
      float s = 0.f;
      for (int q = 0; q < 64; ++q) s += tmp[tid * 64 + q];
      ws->bus[tid] = s;
    }
  } else if (bid < 1037) {
    int l = bid - 1033;
    #pragma unroll
    for (int half = 0; half < 2; ++half) {
      int k = tid + half * 256;
      float acc = 0.f;
      for (int i = 0; i < A; ++i)
        acc += Wp[((long)l * (A + H) + i) * H + k];
      ws->wU[l][k] = acc;
    }
  } else {
    // seed afr[l][pp=0][b] from initial states
    int q = bid - 1037, l = q >> 1, b = q & 1;
    for (int i = tid; i < 32768; i += 256) {
      int half = i & 1, lane = (i >> 1) & 63, kt = (i >> 7) & 15;
      int rt = (i >> 11) & 7, sp = (i >> 14) & 1;
      int g = 16 * rt + (lane & 15);
      int kb = 32 * kt + 8 * (lane >> 4) + 4 * half;
      const float* src = states + ((((long)l * B + b) * H) + A + g) * H + kb;
      unsigned v4[4];
      #pragma unroll
      for (int j = 0; j < 4; ++j) {
        float w = src[j];
        unsigned h = bf16r(w);
        if (sp) h = bf16r(w - __uint_as_float(h << 16));
        v4[j] = h;
      }
      unsigned w0 = v4[0] | (v4[1] << 16), w1 = v4[2] | (v4[3] << 16);
      ws->afr[l][0][b][sp][rt][kt][lane][half] = w0 | ((ull)w1 << 32);
    }
  }
}

// ------------------------------------------------------- main kernel
__global__ __launch_bounds__(NT, 1) void vega_kernel(
    const int* __restrict__ ids, const float* __restrict__ states,
    const float* __restrict__ emb,
    const float* __restrict__ nx_w, const float* __restrict__ nx_b,
    const float* __restrict__ Wp, const float* __restrict__ bp,
    const float* __restrict__ ns_w, const float* __restrict__ ns_b,
    const float* __restrict__ W1, const float* __restrict__ b1,
    const float* __restrict__ W2, const float* __restrict__ b2,
    const float* __restrict__ on_w, const float* __restrict__ on_b,
    const float* __restrict__ head_W, const float* __restrict__ head_b,
    float* __restrict__ out, WS* ws) {
  __shared__ SMem sm;
  const int bid = blockIdx.x, tid = threadIdx.x;
  float* fs = out + LOGITS;

  const int c = bid & 7, j = bid >> 3;
  if (c < 4) {
    // ghost layer c: the 32 blocks with bid%8==c (expected: one XCD).
    const int l = c, ct = j;
    unsigned myx = (unsigned)__builtin_amdgcn_s_getreg(6164);  // HW_REG_XCC_ID[0:3]
    if (tid == 0) {
      __hip_atomic_store(&ws->gxcd[l][ct], myx | 0x100u,
                         __ATOMIC_RELAXED, __HIP_MEMORY_SCOPE_SYSTEM);
      __builtin_amdgcn_s_waitcnt(0);
      __hip_atomic_fetch_add(&ws->gxcnt[l], 1u, __ATOMIC_RELAXED, __HIP_MEMORY_SCOPE_AGENT);
    }
    cwait(&ws->gxcnt[l], (unsigned)NGB);
    unsigned x0 = sload_u(&ws->gxcd[l][0]);
    bool fast = true;
    for (int i = 1; i < NGB; ++i) fast = fast && (sload_u(&ws->gxcd[l][i]) == x0);
    if (fast) ghost_regs<true>(l, ct, ws, sm, states, fs);
    else      ghost_regs<false>(l, ct, ws, sm, states, fs);
  } else {
    x_set(c - 4, j, ws, sm, ids, emb, nx_w, nx_b, Wp, bp,
          ns_w, ns_b, W1, b1, W2, b2);
  }

  gbar(ws);

  // -------- E1: fstates reconstruction (u from lnx) + final LN of outs --------
  if (bid < 192) {
    int lb = bid / 24, sub = bid % 24;
    int l = lb >> 1, b = lb & 1, r0 = sub * 16;
    const long wb = (long)l * (A + H);
    const int row = tid >> 5, kc = tid & 31;
    float wreg[16];
    {
      const float* wr = Wp + (wb + r0 + row) * H + kc * 16;
      #pragma unroll
      for (int jj = 0; jj < 16; ++jj) wreg[jj] = wr[jj];
    }
    const float bprow = bp[wb + r0 + row];
    float pre = sload(&ws->lnxs[0][l][b][tid]);
    for (int t2 = 0; t2 < T; ++t2) {
      sm.e1.lnx[tid] = pre;
      __syncthreads();
      if (t2 + 1 < T) pre = sload(&ws->lnxs[t2 + 1][l][b][tid]);
      float part = 0.f;
      #pragma unroll
      for (int jj = 0; jj < 16; ++jj) part += wreg[jj] * sm.e1.lnx[kc * 16 + jj];
      #pragma unroll
      for (int off = 1; off < 32; off <<= 1) part += __shfl_xor(part, off);
      if (kc == 0) sm.e1.u16[t2][row] = part + bprow;
      __syncthreads();
    }
    float bv = bp[wb + A + tid];
    float acc[16];
    #pragma unroll
    for (int q = 0; q < 16; ++q) acc[q] = 32.f * bp[wb + r0 + q] * bv;
    for (int t2 = 0; t2 < T; ++t2) {
      float vv = sload(&ws->uv[t2][l][b][A + tid]);
      #pragma unroll
      for (int q = 0; q < 16; ++q) acc[q] = fmaf(sm.e1.u16[t2][q], vv, acc[q]);
    }
    #pragma unroll
    for (int q = 0; q < 16; ++q)
      fs[(((long)l * B + b) * H + (r0 + q)) * H + tid] =
          states[(((long)l * B + b) * H + (r0 + q)) * H + tid] + acc[q];
  }
  if (bid < T * B) {
    int row = bid, t = row >> 1, b = row & 1;
    ln512(sm, ws->outs[t][b], ws->lnouts[row], on_w, on_b);
  }

  gbar(ws);

  // -------- E2: head GEMM (64 rows x 125 vocab per block, K=512) --------
  {
    const int wv = tid >> 6, lane = tid & 63;
    const long vbase = (long)bid * 125;
    float acc[16];
    #pragma unroll
    for (int q = 0; q < 16; ++q) acc[q] = 0.f;
    for (int cc = 0; cc < 8; ++cc) {
      float4 xr[16];
      #pragma unroll
      for (int q = 0; q < 16; ++q)
        xr[q] = *(const float4*)&ws->lnouts[lane][cc * 64 + q * 4];
      #pragma unroll
      for (int vi = 0; vi < 16; ++vi) {
        int vloc = vi * 8 + wv;
        if (vloc < 125) {
          const float4* wp_ = (const float4*)(head_W + (vbase + vloc) * H + cc * 64);
          float s = 0.f;
          #pragma unroll
          for (int q = 0; q < 16; ++q) s += dot4(xr[q], wp_[q]);
          acc[vi] += s;
        }
      }
    }
    #pragma unroll
    for (int vi = 0; vi < 16; ++vi) {
      int vloc = vi * 8 + wv;
      if (vloc < 125) sm.hd.tile[vloc][lane] = acc[vi] + head_b[vbase + vloc];
    }
    __syncthreads();
    for (int idx = tid; idx < 64 * 125; idx += NT) {
      int row = idx / 125, vl = idx % 125;
      int t = row >> 1, b = row & 1;
      out[((long)(b * T + t)) * V + vbase + vl] = sm.hd.tile[vl][row];
    }
  }
}

}  // namespace

extern "C" void kernel_launch(void* const* d_in, const int* in_sizes, int n_in,
                              void* d_out, int out_size, void* d_ws, size_t ws_size,
                              hipStream_t stream) {
  (void)in_sizes; (void)n_in; (void)out_size; (void)ws_size;
  const int*   ids    = (const int*)d_in[0];
  const float* states = (const float*)d_in[1];
  const float* emb    = (const float*)d_in[2];
  const float* nx_w   = (const float*)d_in[3];
  const float* nx_b   = (const float*)d_in[4];
  const float* Wp     = (const float*)d_in[5];
  const float* bp     = (const float*)d_in[6];
  const float* Wg     = (const float*)d_in[7];
  const float* Wt     = (const float*)d_in[8];
  const float* ns_w   = (const float*)d_in[9];
  const float* ns_b   = (const float*)d_in[10];
  const float* W1     = (const float*)d_in[11];
  const float* b1     = (const float*)d_in[12];
  const float* W2     = (const float*)d_in[13];
  const float* b2     = (const float*)d_in[14];
  const float* on_w   = (const float*)d_in[15];
  const float* on_b   = (const float*)d_in[16];
  const float* head_W = (const float*)d_in[17];
  const float* head_b = (const float*)d_in[18];
  float* out = (float*)d_out;
  WS* ws = (WS*)d_ws;

  (void)hipMemsetAsync(d_ws, 0, offsetof(WS, uv), stream);
  pack_kernel<<<dim3(1045), dim3(256), 0, stream>>>(Wg, Wt, states, bp, Wp, ws);
  vega_kernel<<<dim3(GRID), dim3(NT), 0, stream>>>(
      ids, states, emb, nx_w, nx_b, Wp, bp, ns_w, ns_b,
      W1, b1, W2, b2, on_w, on_b, head_W, head_b, out, ws);
}

// Round 12
// 1535.232 us; speedup vs baseline: 3.0016x; 1.0683x over previous
//
#include <hip/hip_runtime.h>
#include <hip/hip_bf16.h>
#include <math.h>
#include <stddef.h>

namespace {

constexpr int V = 32000, H = 512, L = 4, A = 384, B = 2, T = 32, FF = 2048;
constexpr long LOGITS = (long)B * T * V;   // 2,048,000
constexpr int GRID = 256, NT = 512;
constexpr int NXR = 32;                    // x roles per layer
constexpr int NGB = 32;                    // ghost blocks per layer (col-sliced)
constexpr float EPS = 1e-5f;

typedef short bf16x8 __attribute__((ext_vector_type(8)));
typedef float f32x4 __attribute__((ext_vector_type(4)));
typedef unsigned long long ull;
typedef unsigned long long ull2 __attribute__((ext_vector_type(2)));

struct WS {
  // ---- zeroed region (flags; no same-address RMW anywhere in steady state) ----
  unsigned gflag[GRID];          // grid-barrier per-block flags
  unsigned grel;                 // grid-barrier release
  unsigned pad0[63];
  unsigned p1f[L][NXR], p2f[L][NXR], p3f[L][NXR];  // x phase flags (= t+1)
  unsigned gbf[L][NGB];          // ghost rec flags (= rec+1)
  unsigned gcf[L][T][NGB];       // ghost colsum flags (= 1)
  unsigned gxcd[L][NGB];         // placement handshake slots (xcd | 0x100)
  unsigned pad2[64];
  float gcol[L][T][B][H];
  // ---- not zeroed (fully written before read every launch) ----
  float uv[T][L][B][A + H];
  float lnxs[T][L][B][H];
  float outs[T][B][H];
  float lnouts[T * B][H];
  float xn[3][T][B][H];
  float hbuf[L][2][B][FF];
  float initcol[L * B * H];
  float bus[4];
  float wU[L][H];
  uint4 bpk[L][2][2][16][32][64];      // ghost W frag-packed (hi/lo split)
  ull afr[L][2][2][2][8][16][64][2];   // A-frag exchange [l][pp][b][split][rt][kt][lane][half]
};

union __align__(16) SMem {
  struct { unsigned xch[8][2][16][16]; float colp[8][2][16]; } gx;  // 17 KB (ghost)
  struct {
    unsigned wp[16][256];   // Wp v-rows, bf16 pair (2m,2m+1)
    unsigned w1[64][256];
    unsigned w2[16][1024];  // pair (2m,2m+1)
    float lnx[2][512];
    unsigned hb[2][1024];   // h as bf16 pairs
    float xms[2][16];
    float2 red[8];
  } xp;                     // ~156 KB
  struct { float u16[T][16]; float lnx[H]; } e1;
  struct { float tile[125][64]; } hd;
};

__device__ __forceinline__ float dot4(const float4& a, const float4& b) {
  return a.x * b.x + a.y * b.y + a.z * b.z + a.w * b.w;
}
__device__ __forceinline__ unsigned bf16r(float f) {
  unsigned u = __float_as_uint(f);
  return (u + 0x7fffu + ((u >> 16) & 1u)) >> 16;
}
// system-scope relaxed: uncached, coherence-point reads/writes
__device__ __forceinline__ float sload(const float* p) {
  return __hip_atomic_load(p, __ATOMIC_RELAXED, __HIP_MEMORY_SCOPE_SYSTEM);
}
__device__ __forceinline__ void sstore(float* p, float v) {
  __hip_atomic_store(p, v, __ATOMIC_RELAXED, __HIP_MEMORY_SCOPE_SYSTEM);
}
__device__ __forceinline__ ull sld64(const ull* p) {
  return __hip_atomic_load(p, __ATOMIC_RELAXED, __HIP_MEMORY_SCOPE_SYSTEM);
}
__device__ __forceinline__ void sst64(ull* p, ull v) {
  __hip_atomic_store(p, v, __ATOMIC_RELAXED, __HIP_MEMORY_SCOPE_SYSTEM);
}
// agent(device)-scope relaxed: bypasses L1, L2-cacheable (r11-proven ghost fabric)
__device__ __forceinline__ ull ald64(const ull* p) {
  return __hip_atomic_load(p, __ATOMIC_RELAXED, __HIP_MEMORY_SCOPE_AGENT);
}
__device__ __forceinline__ void ast64(ull* p, ull v) {
  __hip_atomic_store(p, v, __ATOMIC_RELAXED, __HIP_MEMORY_SCOPE_AGENT);
}
__device__ __forceinline__ unsigned sload_u(const unsigned* p) {
  return __hip_atomic_load(p, __ATOMIC_RELAXED, __HIP_MEMORY_SCOPE_SYSTEM);
}
__device__ __forceinline__ void sstore_u(unsigned* p, unsigned v) {
  __hip_atomic_store(p, v, __ATOMIC_RELAXED, __HIP_MEMORY_SCOPE_SYSTEM);
}
__device__ __forceinline__ f32x4 mfma16(bf16x8 a, bf16x8 b, f32x4 c) {
  return __builtin_amdgcn_mfma_f32_16x16x32_bf16(a, b, c, 0, 0, 0);
}
__device__ __forceinline__ bf16x8 bc2(ull a, ull b) {
  ull2 t; t.x = a; t.y = b;
  return __builtin_bit_cast(bf16x8, t);
}
__device__ __forceinline__ bf16x8 bcu4(uint4 u) {
  return __builtin_bit_cast(bf16x8, u);
}

template <bool FAST>
__device__ __forceinline__ bf16x8 ld_afr(const ull* p) {
  if (FAST) return bc2(ald64(p), ald64(p + 1));
  else      return bc2(sld64(p), sld64(p + 1));
}
template <bool FAST>
__device__ __forceinline__ void st_afr(ull* p, ull lo, ull hi) {
  if (FAST) { ast64(p, lo); ast64(p + 1, hi); }
  else      { sst64(p, lo); sst64(p + 1, hi); }
}

// ---- flag-array sync fabric: plain flag stores + wave-parallel uncached polls ----
// All 64 lanes of wave 0 participate; lanes >= n poll slot 0 with ok=true.
__device__ void poll32(const unsigned* f, unsigned tgt) {
  if (threadIdx.x < 64) {
    const bool act = threadIdx.x < 32;
    const unsigned* p = f + (act ? threadIdx.x : 0);
    for (;;) {
      unsigned v = sload_u(p);
      if (__all(!act || v >= tgt)) break;
      __builtin_amdgcn_s_sleep(1);
    }
  }
  __syncthreads();
}
__device__ void poll_dual(const unsigned* fa, unsigned ta,
                          const unsigned* fb, unsigned tb) {
  if (threadIdx.x < 64) {
    const bool ina = threadIdx.x < 32;
    const unsigned* p = ina ? fa + threadIdx.x : fb + (threadIdx.x - 32);
    const unsigned tg = ina ? ta : tb;
    for (;;) {
      unsigned v = sload_u(p);
      if (__all(v >= tg)) break;
      __builtin_amdgcn_s_sleep(1);
    }
  }
  __syncthreads();
}
// all prior stores (all waves) drained, then tid0 publishes flag
__device__ void setf_sys(unsigned* p, unsigned v) {
  __builtin_amdgcn_s_waitcnt(0);
  __syncthreads();
  if (threadIdx.x == 0) sstore_u(p, v);
}

// grid barrier: flag array + single scanner block, with threadfence (wbl2/inv)
// on both sides to preserve plain-store visibility across XCDs (lnouts path).
__device__ void gbar2(WS* ws, unsigned phase) {
  __builtin_amdgcn_s_waitcnt(0);
  __syncthreads();
  if (threadIdx.x == 0) {
    __threadfence();
    sstore_u(&ws->gflag[blockIdx.x], phase);
  }
  if (blockIdx.x == 0) {
    if (threadIdx.x < 64) {
      for (;;) {
        bool ok = true;
        #pragma unroll
        for (int q = 0; q < 4; ++q)
          ok = ok && (sload_u(&ws->gflag[threadIdx.x * 4 + q]) >= phase);
        if (__all(ok)) break;
        __builtin_amdgcn_s_sleep(1);
      }
    }
    __syncthreads();
    if (threadIdx.x == 0) sstore_u(&ws->grel, phase);
  }
  if (threadIdx.x == 0) {
    while (sload_u(&ws->grel) < phase) __builtin_amdgcn_s_sleep(1);
    __threadfence();
  }
  __syncthreads();
}

__device__ float2 wred2(float2 v) {
  #pragma unroll
  for (int off = 1; off < 64; off <<= 1) {
    v.x += __shfl_xor(v.x, off);
    v.y += __shfl_xor(v.y, off);
  }
  return v;
}

__device__ float2 block_red2(float2 v, SMem& sm) {
  v = wred2(v);
  int w = threadIdx.x >> 6;
  __syncthreads();
  if ((threadIdx.x & 63) == 0) sm.xp.red[w] = v;
  __syncthreads();
  float2 s{0.f, 0.f};
  #pragma unroll
  for (int q = 0; q < 8; ++q) { s.x += sm.xp.red[q].x; s.y += sm.xp.red[q].y; }
  return s;
}

__device__ void ln512(SMem& sm, const float* in, float* outp,
                      const float* w, const float* b) {
  int tid = threadIdx.x;
  float xv = in[tid];
  float m = block_red2({xv, 0.f}, sm).x * (1.f / H);
  float d = xv - m;
  float var = block_red2({d * d, 0.f}, sm).x * (1.f / H);
  float inv = rsqrtf(var + EPS);
  outp[tid] = d * inv * w[tid] + b[tid];
  __syncthreads();
}

__device__ float2 ln2reg(SMem& sm, float x0, float x1, const float* w, const float* b) {
  int tid = threadIdx.x;
  float2 mm = block_red2({x0, x1}, sm);
  float d0 = x0 - mm.x * (1.f / H), d1 = x1 - mm.y * (1.f / H);
  float2 vv = block_red2({d0 * d0, d1 * d1}, sm);
  float i0 = rsqrtf(vv.x * (1.f / H) + EPS), i1 = rsqrtf(vv.y * (1.f / H) + EPS);
  float wv_ = w[tid], bv = b[tid];
  float l0 = d0 * i0 * wv_ + bv, l1 = d1 * i1 * wv_ + bv;
  sm.xp.lnx[0][tid] = l0;
  sm.xp.lnx[1][tid] = l1;
  __syncthreads();
  return {l0, l1};
}

__device__ __forceinline__ float2 d8(uint4 wq, const float* xr0, const float* xr1) {
  float2 a{0.f, 0.f};
  unsigned u[4] = {wq.x, wq.y, wq.z, wq.w};
  #pragma unroll
  for (int j = 0; j < 4; ++j) {
    float wl = __uint_as_float(u[j] << 16);
    float wh = __uint_as_float(u[j] & 0xffff0000u);
    a.x = fmaf(wl, xr0[2 * j], fmaf(wh, xr0[2 * j + 1], a.x));
    a.y = fmaf(wl, xr1[2 * j], fmaf(wh, xr1[2 * j + 1], a.y));
  }
  return a;
}

// ------------------------------------------------------- ghost
template <bool FAST>
__device__ void ghost_regs(int l, int ct, WS* ws, SMem& sm,
                           const float* __restrict__ states, float* __restrict__ fs) {
  const int tid = threadIdx.x, wv = tid >> 6, lane = tid & 63;
  const int c15 = lane & 15, lq = lane >> 4;
  float ms[2][4];
  #pragma unroll
  for (int b = 0; b < 2; ++b)
    #pragma unroll
    for (int r = 0; r < 4; ++r)
      ms[b][r] = states[((((long)l * B + b) * H) + A + 16 * wv + 4 * lq + r) * H + 16 * ct + c15];

  const int ktp = ct >> 1;
  const int lt_base = 32 * (ct & 1);

  #pragma unroll 1
  for (int rec = 0; rec < 2 * T; ++rec) {
    const int pp = rec & 1, np = pp ^ 1;
    asm volatile("" ::: "memory");
    f32x4 accg[2], acct[2];
    #pragma unroll
    for (int b = 0; b < 2; ++b) { accg[b] = {0.f,0.f,0.f,0.f}; acct[b] = {0.f,0.f,0.f,0.f}; }
    #pragma unroll 4
    for (int kt = 0; kt < 16; ++kt) {
      bf16x8 a00 = ld_afr<FAST>(&ws->afr[l][pp][0][0][wv][kt][lane][0]);
      bf16x8 a01 = ld_afr<FAST>(&ws->afr[l][pp][0][1][wv][kt][lane][0]);
      bf16x8 a10 = ld_afr<FAST>(&ws->afr[l][pp][1][0][wv][kt][lane][0]);
      bf16x8 a11 = ld_afr<FAST>(&ws->afr[l][pp][1][1][wv][kt][lane][0]);
      bf16x8 bgh = bcu4(ws->bpk[l][0][0][kt][ct][lane]);
      bf16x8 bgl = bcu4(ws->bpk[l][0][1][kt][ct][lane]);
      bf16x8 bth = bcu4(ws->bpk[l][1][0][kt][ct][lane]);
      bf16x8 btl = bcu4(ws->bpk[l][1][1][kt][ct][lane]);
      accg[0] = mfma16(a00, bgh, accg[0]);
      accg[0] = mfma16(a00, bgl, accg[0]);
      accg[0] = mfma16(a01, bgh, accg[0]);
      acct[0] = mfma16(a00, bth, acct[0]);
      acct[0] = mfma16(a00, btl, acct[0]);
      acct[0] = mfma16(a01, bth, acct[0]);
      accg[1] = mfma16(a10, bgh, accg[1]);
      accg[1] = mfma16(a10, bgl, accg[1]);
      accg[1] = mfma16(a11, bgh, accg[1]);
      acct[1] = mfma16(a10, bth, acct[1]);
      acct[1] = mfma16(a10, btl, acct[1]);
      acct[1] = mfma16(a11, bth, acct[1]);
    }
    const int t = rec >> 1;
    const bool pub = (rec & 1) != 0;
    #pragma unroll
    for (int b = 0; b < 2; ++b) {
      float css = 0.f;
      #pragma unroll
      for (int r = 0; r < 4; ++r) {
        float sig = 1.f / (1.f + expf(-accg[b][r]));
        float nv = ms[b][r] + sig * tanhf(acct[b][r]);
        ms[b][r] = nv;
        css += nv;
        unsigned hi = bf16r(nv);
        unsigned lo = bf16r(nv - __uint_as_float(hi << 16));
        sm.gx.xch[wv][b][4 * lq + r][c15] = hi | (lo << 16);
      }
      if (pub) {
        css += __shfl_xor(css, 16);
        css += __shfl_xor(css, 32);
        if (lane < 16) sm.gx.colp[wv][b][lane] = css;
      }
    }
    __syncthreads();
    // publish A-fragments for next rec
    {
      const int b = lane >> 5, o2 = (lane >> 4) & 1, row = lane & 15;
      unsigned x[8];
      #pragma unroll
      for (int j = 0; j < 8; ++j) x[j] = sm.gx.xch[wv][b][row][o2 * 8 + j];
      unsigned hw[4], lw[4];
      #pragma unroll
      for (int j = 0; j < 4; ++j) {
        hw[j] = (x[2 * j] & 0xffffu) | ((x[2 * j + 1] & 0xffffu) << 16);
        lw[j] = (x[2 * j] >> 16) | (x[2 * j + 1] & 0xffff0000u);
      }
      const int lt = lt_base + 16 * o2 + row;
      st_afr<FAST>(&ws->afr[l][np][b][0][wv][ktp][lt][0],
                   hw[0] | ((ull)hw[1] << 32), hw[2] | ((ull)hw[3] << 32));
      st_afr<FAST>(&ws->afr[l][np][b][1][wv][ktp][lt][0],
                   lw[0] | ((ull)lw[1] << 32), lw[2] | ((ull)lw[3] << 32));
    }
    if (pub && tid < 32) {
      int b = tid >> 4, c = tid & 15;
      float s = 0.f;
      #pragma unroll
      for (int w = 0; w < 8; ++w) s += sm.gx.colp[w][b][c];
      sstore(&ws->gcol[l][t][b][16 * ct + c], s);  // exclusive col owner
    }
    asm volatile("" ::: "memory");
    __builtin_amdgcn_s_waitcnt(0);
    __syncthreads();
    if (tid == 0) {
      sstore_u(&ws->gbf[l][ct], (unsigned)(rec + 1));
      if (pub) sstore_u(&ws->gcf[l][t][ct], 1u);
    }
    if (rec + 1 < 2 * T) poll32(ws->gbf[l], (unsigned)(rec + 1));
  }
  #pragma unroll
  for (int b = 0; b < 2; ++b)
    #pragma unroll
    for (int r = 0; r < 4; ++r)
      fs[((((long)l * B + b) * H) + A + 16 * wv + 4 * lq + r) * H + 16 * ct + c15] = ms[b][r];
}

// ------------------------------------------------------- x layer-set (32 roles)
__device__ void x_set(int l, int role, WS* ws, SMem& sm,
                      const int* ids, const float* emb,
                      const float* nx_w, const float* nx_b,
                      const float* Wp, const float* bp,
                      const float* ns_w, const float* ns_b,
                      const float* W1, const float* b1,
                      const float* W2, const float* b2) {
  const int tid = threadIdx.x, wv = tid >> 6, lane = tid & 63;
  const long wb = (long)l * (A + H);
  const int v0r = role * 16, a0 = role * 64, c0 = role * 16;

  for (int i = tid; i < 16 * 256; i += NT) {
    int row = i >> 8, m = i & 255;
    const float* s = Wp + (wb + A + v0r + row) * H + 2 * m;
    sm.xp.wp[row][m] = bf16r(s[0]) | (bf16r(s[1]) << 16);
  }
  for (int i = tid; i < 64 * 256; i += NT) {
    int row = i >> 8, m = i & 255;
    const float* s = W1 + ((long)l * FF + a0 + row) * H + 2 * m;
    sm.xp.w1[row][m] = bf16r(s[0]) | (bf16r(s[1]) << 16);
  }
  for (int i = tid; i < 16 * 1024; i += NT) {
    int row = i >> 10, m = i & 1023;
    const float* s = W2 + ((long)l * H + c0 + row) * FF + 2 * m;
    sm.xp.w2[row][m] = bf16r(s[0]) | (bf16r(s[1]) << 16);
  }
  const float ic0 = ws->initcol[(l * B + 0) * H + tid];
  const float ic1 = ws->initcol[(l * B + 1) * H + tid];
  const float BU = ws->bus[l];
  const float bpA = bp[wb + A + tid];
  const float wU0 = ws->wU[l][tid];
  float as0 = 0.f, as1 = 0.f;
  __syncthreads();

  for (int t = 0; t < T; ++t) {
    // ---- P0 ----
    float xm0, xm1;
    if (l == 0) {
      xm0 = emb[(long)ids[t] * H + tid];
      xm1 = emb[(long)ids[T + t] * H + tid];
    } else {
      poll32(ws->p3f[l - 1], (unsigned)(t + 1));
      xm0 = sload(&ws->xn[l - 1][t][0][tid]);
      xm1 = sload(&ws->xn[l - 1][t][1][tid]);
    }
    // ---- P1: LN1 + v-slice ----
    float2 ln = ln2reg(sm, xm0, xm1, nx_w + l * H, nx_b + l * H);
    float xr0[8], xr1[8];
    #pragma unroll
    for (int j = 0; j < 8; ++j) { xr0[j] = sm.xp.lnx[0][lane * 8 + j]; xr1[j] = sm.xp.lnx[1][lane * 8 + j]; }
    #pragma unroll
    for (int it = 0; it < 2; ++it) {
      int row = v0r + wv + it * 8;
      uint4 wq = *(const uint4*)&sm.xp.wp[row - v0r][lane * 4];
      float2 acc = wred2(d8(wq, xr0, xr1));
      if (lane == 0) {
        float bb = bp[wb + A + row];
        sstore(&ws->uv[t][l][0][A + row], acc.x + bb);
        sstore(&ws->uv[t][l][1][A + row], acc.y + bb);
      }
    }
    if (tid >= v0r && tid < v0r + 16) {
      sstore(&ws->lnxs[t][l][0][tid], ln.x);
      sstore(&ws->lnxs[t][l][1][tid], ln.y);
    }
    setf_sys(&ws->p1f[l][role], (unsigned)(t + 1));
    float2 U1 = block_red2({wU0 * ln.x, wU0 * ln.y}, sm);
    poll_dual(ws->p1f[l], (unsigned)(t + 1), ws->gcf[l][t], 1u);
    // ---- P2: asum, xm, LN2, W1 ----
    float v0 = sload(&ws->uv[t][l][0][A + tid]);
    float v1 = sload(&ws->uv[t][l][1][A + tid]);
    float gc0 = sload(&ws->gcol[l][t][0][tid]);
    float gc1 = sload(&ws->gcol[l][t][1][tid]);
    as0 += (U1.x + BU) * v0;
    as1 += (U1.y + BU) * v1;
    float tb = (float)(t + 1) * BU * bpA;
    xm0 += (as0 + ic0 + tb + gc0) * (1.f / H);
    xm1 += (as1 + ic1 + tb + gc1) * (1.f / H);
    if (tid >= c0 && tid < c0 + 16) { sm.xp.xms[0][tid - c0] = xm0; sm.xp.xms[1][tid - c0] = xm1; }
    ln = ln2reg(sm, xm0, xm1, ns_w + l * H, ns_b + l * H);
    #pragma unroll
    for (int j = 0; j < 8; ++j) { xr0[j] = sm.xp.lnx[0][lane * 8 + j]; xr1[j] = sm.xp.lnx[1][lane * 8 + j]; }
    #pragma unroll
    for (int it = 0; it < 8; ++it) {
      int row = a0 + wv + it * 8;
      uint4 wq = *(const uint4*)&sm.xp.w1[row - a0][lane * 4];
      float2 acc = wred2(d8(wq, xr0, xr1));
      if (lane == 0) {
        float bb = b1[(long)l * FF + row];
        float z0 = acc.x + bb, z1 = acc.y + bb;
        sstore(&ws->hbuf[l][t & 1][0][row], 0.5f * z0 * (1.f + erff(z0 * 0.70710678118f)));
        sstore(&ws->hbuf[l][t & 1][1][row], 0.5f * z1 * (1.f + erff(z1 * 0.70710678118f)));
      }
    }
    setf_sys(&ws->p2f[l][role], (unsigned)(t + 1));
    poll32(ws->p2f[l], (unsigned)(t + 1));
    // ---- P3: gather h (bf16), W2, residual ----
    for (int i = tid; i < 2048; i += NT) {
      int b = i >> 10, m = i & 1023;
      ull hv = sld64((const ull*)&ws->hbuf[l][t & 1][b][2 * m]);
      float h0 = __uint_as_float((unsigned)hv);
      float h1 = __uint_as_float((unsigned)(hv >> 32));
      sm.xp.hb[b][m] = bf16r(h0) | (bf16r(h1) << 16);
    }
    __syncthreads();
    unsigned h0r[16], h1r[16];
    #pragma unroll
    for (int q = 0; q < 16; ++q) { h0r[q] = sm.xp.hb[0][lane + 64 * q]; h1r[q] = sm.xp.hb[1][lane + 64 * q]; }
    #pragma unroll
    for (int it = 0; it < 2; ++it) {
      int row = c0 + wv + it * 8;
      float2 acc{0.f, 0.f};
      #pragma unroll
      for (int q = 0; q < 16; ++q) {
        unsigned w = sm.xp.w2[row - c0][lane + 64 * q];
        float wl = __uint_as_float(w << 16), wh = __uint_as_float(w & 0xffff0000u);
        acc.x += wl * __uint_as_float(h0r[q] << 16) + wh * __uint_as_float(h0r[q] & 0xffff0000u);
        acc.y += wl * __uint_as_float(h1r[q] << 16) + wh * __uint_as_float(h1r[q] & 0xffff0000u);
      }
      acc = wred2(acc);
      if (lane == 0) {
        float bb = b2[(long)l * H + row];
        float o0 = sm.xp.xms[0][row - c0] + acc.x + bb;
        float o1 = sm.xp.xms[1][row - c0] + acc.y + bb;
        if (l == L - 1) {
          sstore(&ws->outs[t][0][row], o0);
          sstore(&ws->outs[t][1][row], o1);
        } else {
          sstore(&ws->xn[l][t][0][row], o0);
          sstore(&ws->xn[l][t][1][row], o1);
        }
      }
    }
    setf_sys(&ws->p3f[l][role], (unsigned)(t + 1));
    __syncthreads();
  }
}

// ------------------------------------------------------- prologue pack
__global__ __launch_bounds__(256) void pack_kernel(const float* __restrict__ Wg,
                                                   const float* __restrict__ Wt,
                                                   const float* __restrict__ states,
                                                   const float* __restrict__ bp,
                                                   const float* __restrict__ Wp,
                                                   WS* ws) {
  const int bid = blockIdx.x, tid = threadIdx.x;
  if (bid < 1024) {
    #pragma unroll
    for (int rep = 0; rep < 2; ++rep) {
      unsigned f = (unsigned)bid * 512u + (unsigned)rep * 256u + (unsigned)tid;
      int lane = f & 63, ct = (f >> 6) & 31, kt = (f >> 11) & 15;
      int split = (f >> 15) & 1, mat = (f >> 16) & 1, l = f >> 17;
      int o = ct * 16 + (lane & 15), kb = kt * 32 + ((lane >> 4) << 3);
      const float* src = (mat ? Wt : Wg) + ((long)l * H + o) * H + kb;
      unsigned v8[8];
      #pragma unroll
      for (int j = 0; j < 8; ++j) {
        float w = src[j];
        unsigned h = bf16r(w);
        if (split) h = bf16r(w - __uint_as_float(h << 16));
        v8[j] = h;
      }
      uint4 u;
      u.x = v8[0] | (v8[1] << 16); u.y = v8[2] | (v8[3] << 16);
      u.z = v8[4] | (v8[5] << 16); u.w = v8[6] | (v8[7] << 16);
      ws->bpk[l][mat][split][kt][ct][lane] = u;
    }
  } else if (bid < 1032) {
    int lb = bid - 1024, l = lb >> 1, b = lb & 1;
    #pragma unroll
    for (int half = 0; half < 2; ++half) {
      int col = tid + half * 256;
      float acc = 0.f;
      for (int i = 0; i < A; ++i)
        acc += states[(((long)l * B + b) * H + i) * H + col];
      ws->initcol[(l * B + b) * H + col] = acc;
    }
  } else if (bid == 1032) {
    __shared__ float tmp[256];
    int l = tid >> 6, i = tid & 63;
    float p = 0.f;
    for (int j = 0; j < 6; ++j) p += bp[(long)l * (A + H) + j * 64 + i];
    tmp[tid] = p;
    __syncthreads();
    if (tid < 4) {
      float s = 0.f;
      for (int q = 0; q < 64; ++q) s += tmp[tid * 64 + q];
      ws->bus[tid] = s;
    }
  } else if (bid < 1037) {
    int l = bid - 1033;
    #pragma unroll
    for (int half = 0; half < 2; ++half) {
      int k = tid + half * 256;
      float acc = 0.f;
      for (int i = 0; i < A; ++i)
        acc += Wp[((long)l * (A + H) + i) * H + k];
      ws->wU[l][k] = acc;
    }
  } else {
    // seed afr[l][pp=0][b] from initial states
    int q = bid - 1037, l = q >> 1, b = q & 1;
    for (int i = tid; i < 32768; i += 256) {
      int half = i & 1, lane = (i >> 1) & 63, kt = (i >> 7) & 15;
      int rt = (i >> 11) & 7, sp = (i >> 14) & 1;
      int g = 16 * rt + (lane & 15);
      int kb = 32 * kt + 8 * (lane >> 4) + 4 * half;
      const float* src = states + ((((long)l * B + b) * H) + A + g) * H + kb;
      unsigned v4[4];
      #pragma unroll
      for (int j = 0; j < 4; ++j) {
        float w = src[j];
        unsigned h = bf16r(w);
        if (sp) h = bf16r(w - __uint_as_float(h << 16));
        v4[j] = h;
      }
      unsigned w0 = v4[0] | (v4[1] << 16), w1 = v4[2] | (v4[3] << 16);
      ws->afr[l][0][b][sp][rt][kt][lane][half] = w0 | ((ull)w1 << 32);
    }
  }
}

// ------------------------------------------------------- main kernel
__global__ __launch_bounds__(NT, 1) void vega_kernel(
    const int* __restrict__ ids, const float* __restrict__ states,
    const float* __restrict__ emb,
    const float* __restrict__ nx_w, const float* __restrict__ nx_b,
    const float* __restrict__ Wp, const float* __restrict__ bp,
    const float* __restrict__ ns_w, const float* __restrict__ ns_b,
    const float* __restrict__ W1, const float* __restrict__ b1,
    const float* __restrict__ W2, const float* __restrict__ b2,
    const float* __restrict__ on_w, const float* __restrict__ on_b,
    const float* __restrict__ head_W, const float* __restrict__ head_b,
    float* __restrict__ out, WS* ws) {
  __shared__ SMem sm;
  const int bid = blockIdx.x, tid = threadIdx.x;
  float* fs = out + LOGITS;

  const int c = bid & 7, j = bid >> 3;
  if (c < 4) {
    // ghost layer c: the 32 blocks with bid%8==c (expected: one XCD).
    const int l = c, ct = j;
    unsigned myx = (unsigned)__builtin_amdgcn_s_getreg(6164);  // HW_REG_XCC_ID[0:3]
    if (tid == 0) sstore_u(&ws->gxcd[l][ct], myx | 0x100u);
    poll32(ws->gxcd[l], 0x100u);
    unsigned x0 = sload_u(&ws->gxcd[l][0]);
    bool fast = true;
    for (int i = 1; i < NGB; ++i) fast = fast && (sload_u(&ws->gxcd[l][i]) == x0);
    if (fast) ghost_regs<true>(l, ct, ws, sm, states, fs);
    else      ghost_regs<false>(l, ct, ws, sm, states, fs);
  } else {
    x_set(c - 4, j, ws, sm, ids, emb, nx_w, nx_b, Wp, bp,
          ns_w, ns_b, W1, b1, W2, b2);
  }

  gbar2(ws, 1u);

  // -------- E1: fstates reconstruction (u from lnx) + final LN of outs --------
  if (bid < 192) {
    int lb = bid / 24, sub = bid % 24;
    int l = lb >> 1, b = lb & 1, r0 = sub * 16;
    const long wb = (long)l * (A + H);
    const int row = tid >> 5, kc = tid & 31;
    float wreg[16];
    {
      const float* wr = Wp + (wb + r0 + row) * H + kc * 16;
      #pragma unroll
      for (int jj = 0; jj < 16; ++jj) wreg[jj] = wr[jj];
    }
    const float bprow = bp[wb + r0 + row];
    float pre = sload(&ws->lnxs[0][l][b][tid]);
    for (int t2 = 0; t2 < T; ++t2) {
      sm.e1.lnx[tid] = pre;
      __syncthreads();
      if (t2 + 1 < T) pre = sload(&ws->lnxs[t2 + 1][l][b][tid]);
      float part = 0.f;
      #pragma unroll
      for (int jj = 0; jj < 16; ++jj) part += wreg[jj] * sm.e1.lnx[kc * 16 + jj];
      #pragma unroll
      for (int off = 1; off < 32; off <<= 1) part += __shfl_xor(part, off);
      if (kc == 0) sm.e1.u16[t2][row] = part + bprow;
      __syncthreads();
    }
    float bv = bp[wb + A + tid];
    float acc[16];
    #pragma unroll
    for (int q = 0; q < 16; ++q) acc[q] = 32.f * bp[wb + r0 + q] * bv;
    for (int t2 = 0; t2 < T; ++t2) {
      float vv = sload(&ws->uv[t2][l][b][A + tid]);
      #pragma unroll
      for (int q = 0; q < 16; ++q) acc[q] = fmaf(sm.e1.u16[t2][q], vv, acc[q]);
    }
    #pragma unroll
    for (int q = 0; q < 16; ++q)
      fs[(((long)l * B + b) * H + (r0 + q)) * H + tid] =
          states[(((long)l * B + b) * H + (r0 + q)) * H + tid] + acc[q];
  }
  if (bid < T * B) {
    int row = bid, t = row >> 1, b = row & 1;
    ln512(sm, ws->outs[t][b], ws->lnouts[row], on_w, on_b);
  }

  gbar2(ws, 2u);

  // -------- E2: head GEMM (64 rows x 125 vocab per block, K=512) --------
  {
    const int wv = tid >> 6, lane = tid & 63;
    const long vbase = (long)bid * 125;
    float acc[16];
    #pragma unroll
    for (int q = 0; q < 16; ++q) acc[q] = 0.f;
    for (int cc = 0; cc < 8; ++cc) {
      float4 xr[16];
      #pragma unroll
      for (int q = 0; q < 16; ++q)
        xr[q] = *(const float4*)&ws->lnouts[lane][cc * 64 + q * 4];
      #pragma unroll
      for (int vi = 0; vi < 16; ++vi) {
        int vloc = vi * 8 + wv;
        if (vloc < 125) {
          const float4* wp_ = (const float4*)(head_W + (vbase + vloc) * H + cc * 64);
          float s = 0.f;
          #pragma unroll
          for (int q = 0; q < 16; ++q) s += dot4(xr[q], wp_[q]);
          acc[vi] += s;
        }
      }
    }
    #pragma unroll
    for (int vi = 0; vi < 16; ++vi) {
      int vloc = vi * 8 + wv;
      if (vloc < 125) sm.hd.tile[vloc][lane] = acc[vi] + head_b[vbase + vloc];
    }
    __syncthreads();
    for (int idx = tid; idx < 64 * 125; idx += NT) {
      int row = idx / 125, vl = idx % 125;
      int t = row >> 1, b = row & 1;
      out[((long)(b * T + t)) * V + vbase + vl] = sm.hd.tile[vl][row];
    }
  }
}

}  // namespace

extern "C" void kernel_launch(void* const* d_in, const int* in_sizes, int n_in,
                              void* d_out, int out_size, void* d_ws, size_t ws_size,
                              hipStream_t stream) {
  (void)in_sizes; (void)n_in; (void)out_size; (void)ws_size;
  const int*   ids    = (const int*)d_in[0];
  const float* states = (const float*)d_in[1];
  const float* emb    = (const float*)d_in[2];
  const float* nx_w   = (const float*)d_in[3];
  const float* nx_b   = (const float*)d_in[4];
  const float* Wp     = (const float*)d_in[5];
  const float* bp     = (const float*)d_in[6];
  const float* Wg     = (const float*)d_in[7];
  const float* Wt     = (const float*)d_in[8];
  const float* ns_w   = (const float*)d_in[9];
  const float* ns_b   = (const float*)d_in[10];
  const float* W1     = (const float*)d_in[11];
  const float* b1     = (const float*)d_in[12];
  const float* W2     = (const float*)d_in[13];
  const float* b2     = (const float*)d_in[14];
  const float* on_w   = (const float*)d_in[15];
  const float* on_b   = (const float*)d_in[16];
  const float* head_W = (const float*)d_in[17];
  const float* head_b = (const float*)d_in[18];
  float* out = (float*)d_out;
  WS* ws = (WS*)d_ws;

  (void)hipMemsetAsync(d_ws, 0, offsetof(WS, uv), stream);
  pack_kernel<<<dim3(1045), dim3(256), 0, stream>>>(Wg, Wt, states, bp, Wp, ws);
  vega_kernel<<<dim3(GRID), dim3(NT), 0, stream>>>(
      ids, states, emb, nx_w, nx_b, Wp, bp, ns_w, ns_b,
      W1, b1, W2, b2, on_w, on_b, head_W, head_b, out, ws);
}